// Round 1
// baseline (2216.557 us; speedup 1.0000x reference)
//
#include <hip/hip_runtime.h>
#include <math.h>

#define BATCH 4
#define NN 2048
#define DD 256
#define HH 2048
#define DP 64
#define KTOP 16

// ---------------- Stage 1: Q/K/proj projections + pn normalize ----------------
// grid: BATCH*NN/4 blocks, 64 threads. Each block: 4 rows.
__global__ __launch_bounds__(64) void proj_kernel(
    const float* __restrict__ act,
    const float* __restrict__ Wq, const float* __restrict__ bq,
    const float* __restrict__ Wk, const float* __restrict__ bk,
    const float* __restrict__ Wc, const float* __restrict__ bc,
    float* __restrict__ Qo, float* __restrict__ Ko, float* __restrict__ Pno)
{
    const int row0 = blockIdx.x * 4;
    const int t = threadIdx.x;
    __shared__ float rowbuf[4][DD];
    const float* src = act + (size_t)row0 * DD;
    for (int i = t; i < 4 * DD; i += 64) rowbuf[i >> 8][i & 255] = src[i];
    __syncthreads();

    float q[4], k[4], c[4];
    #pragma unroll
    for (int r = 0; r < 4; ++r) { q[r] = bq[t]; k[r] = bk[t]; c[r] = bc[t]; }

    for (int d = 0; d < DD; ++d) {
        float wq = Wq[d * DP + t];
        float wk = Wk[d * DP + t];
        float wc = Wc[d * DP + t];
        #pragma unroll
        for (int r = 0; r < 4; ++r) {
            float av = rowbuf[r][d];
            q[r] = fmaf(av, wq, q[r]);
            k[r] = fmaf(av, wk, k[r]);
            c[r] = fmaf(av, wc, c[r]);
        }
    }
    #pragma unroll
    for (int r = 0; r < 4; ++r) {
        float ss = c[r] * c[r];
        #pragma unroll
        for (int off = 32; off; off >>= 1) ss += __shfl_xor(ss, off);
        float nrm = fmaxf(sqrtf(ss), 1e-12f);
        size_t o = (size_t)(row0 + r) * DP + t;
        Qo[o] = q[r];
        Ko[o] = k[r];
        Pno[o] = c[r] / nrm;
    }
}

// ---------------- Stage 2: scores + top-16 + softmax + sparse incoming ----------------
// grid: BATCH*NN blocks, 256 threads.
__global__ __launch_bounds__(256) void attn_kernel(
    const float* __restrict__ Q, const float* __restrict__ K,
    const float* __restrict__ states, const float* __restrict__ log_temp,
    float* __restrict__ incoming)
{
    const int row = blockIdx.x;        // b*NN + n
    const int b = row >> 11;
    const int t = threadIdx.x;
    __shared__ alignas(16) float qrow[DP];
    __shared__ float s[NN];
    __shared__ float rv[256];
    __shared__ int   ri[256];
    __shared__ float selw[KTOP];
    __shared__ int   seli[KTOP];
    __shared__ float invZ_sh;

    if (t < DP) qrow[t] = Q[(size_t)row * DP + t];
    __syncthreads();

    float temp = fminf(fmaxf(expf(log_temp[0]), 0.1f), 10.0f);
    float scale = 1.0f / (8.0f * temp);   // SCALE = sqrt(64) = 8

    const float* Kb = K + (size_t)b * NN * DP;
    for (int m = t; m < NN; m += 256) {
        const float4* kr = (const float4*)(Kb + (size_t)m * DP);
        const float4* qr = (const float4*)qrow;
        float acc = 0.0f;
        #pragma unroll
        for (int d4 = 0; d4 < 16; ++d4) {
            float4 kv = kr[d4];
            float4 qv = qr[d4];
            acc = fmaf(kv.x, qv.x, fmaf(kv.y, qv.y, fmaf(kv.z, qv.z, fmaf(kv.w, qv.w, acc))));
        }
        s[m] = acc * scale;
    }
    __syncthreads();

    // iterative top-16 argmax (tie-break: lowest index, matching lax.top_k)
    for (int it = 0; it < KTOP; ++it) {
        float bv = -INFINITY; int bi = 0x7FFFFFFF;
        for (int m = t; m < NN; m += 256) {
            float v = s[m];
            if (v > bv || (v == bv && m < bi)) { bv = v; bi = m; }
        }
        rv[t] = bv; ri[t] = bi;
        __syncthreads();
        for (int off = 128; off; off >>= 1) {
            if (t < off) {
                float v2 = rv[t + off]; int i2 = ri[t + off];
                if (v2 > rv[t] || (v2 == rv[t] && i2 < ri[t])) { rv[t] = v2; ri[t] = i2; }
            }
            __syncthreads();
        }
        if (t == 0) { selw[it] = rv[0]; seli[it] = ri[0]; s[ri[0]] = -INFINITY; }
        __syncthreads();
    }
    if (t == 0) {
        float mx = selw[0];      // values are in descending order
        float Z = 0.0f;
        for (int i = 0; i < KTOP; ++i) { float w = expf(selw[i] - mx); selw[i] = w; Z += w; }
        invZ_sh = 1.0f / Z;
    }
    __syncthreads();

    const float* Sb = states + (size_t)b * NN * DD;
    float invZ = invZ_sh;
    float acc = 0.0f;
    #pragma unroll 4
    for (int kk = 0; kk < KTOP; ++kk)
        acc = fmaf(selw[kk], Sb[(size_t)seli[kk] * DD + t], acc);
    incoming[(size_t)row * DD + t] = acc * invZ;
}

// ---------------- Stage 3: coalition weights + combined + mixed ----------------
// grid: BATCH*(NN/4) blocks, 256 threads. Each block: 4 n-rows, all 256 d.
__global__ __launch_bounds__(256) void coal_kernel(
    const float* __restrict__ pn, const float* __restrict__ incoming,
    const float* __restrict__ temp_coal, float* __restrict__ mixed)
{
    const int blk = blockIdx.x;
    const int b = blk >> 9;              // 512 groups per batch
    const int n0 = (blk & 511) * 4;
    const int t = threadIdx.x;
    __shared__ float4 w4[NN];            // 32 KB: weights for the 4 rows
    __shared__ alignas(16) float pr[4][DP];
    __shared__ float wred[4][4];

    const float* pnb = pn + (size_t)b * NN * DP;
    { int r = t >> 6, d = t & 63; pr[r][d] = pnb[(size_t)(n0 + r) * DP + d]; }
    __syncthreads();

    float tc = temp_coal[0];
    float p0 = 0, p1 = 0, p2 = 0, p3 = 0;
    for (int m = t; m < NN; m += 256) {
        const float4* pm = (const float4*)(pnb + (size_t)m * DP);
        float a0 = 0, a1 = 0, a2 = 0, a3 = 0;
        #pragma unroll
        for (int d4 = 0; d4 < 16; ++d4) {
            float4 v = pm[d4];
            float4 r0 = ((const float4*)pr[0])[d4];
            float4 r1 = ((const float4*)pr[1])[d4];
            float4 r2 = ((const float4*)pr[2])[d4];
            float4 r3 = ((const float4*)pr[3])[d4];
            a0 = fmaf(v.x, r0.x, fmaf(v.y, r0.y, fmaf(v.z, r0.z, fmaf(v.w, r0.w, a0))));
            a1 = fmaf(v.x, r1.x, fmaf(v.y, r1.y, fmaf(v.z, r1.z, fmaf(v.w, r1.w, a1))));
            a2 = fmaf(v.x, r2.x, fmaf(v.y, r2.y, fmaf(v.z, r2.z, fmaf(v.w, r2.w, a2))));
            a3 = fmaf(v.x, r3.x, fmaf(v.y, r3.y, fmaf(v.z, r3.z, fmaf(v.w, r3.w, a3))));
        }
        float s0 = 1.0f / (1.0f + expf(-(a0 - 0.7f) * tc));
        float s1 = 1.0f / (1.0f + expf(-(a1 - 0.7f) * tc));
        float s2 = 1.0f / (1.0f + expf(-(a2 - 0.7f) * tc));
        float s3 = 1.0f / (1.0f + expf(-(a3 - 0.7f) * tc));
        w4[m] = make_float4(s0, s1, s2, s3);
        p0 += s0; p1 += s1; p2 += s2; p3 += s3;
    }
    #pragma unroll
    for (int off = 32; off; off >>= 1) {
        p0 += __shfl_xor(p0, off); p1 += __shfl_xor(p1, off);
        p2 += __shfl_xor(p2, off); p3 += __shfl_xor(p3, off);
    }
    int wid = t >> 6, lane = t & 63;
    if (lane == 0) { wred[wid][0] = p0; wred[wid][1] = p1; wred[wid][2] = p2; wred[wid][3] = p3; }
    __syncthreads();
    float inv0 = 1.0f / (wred[0][0] + wred[1][0] + wred[2][0] + wred[3][0] + 1e-8f);
    float inv1 = 1.0f / (wred[0][1] + wred[1][1] + wred[2][1] + wred[3][1] + 1e-8f);
    float inv2 = 1.0f / (wred[0][2] + wred[1][2] + wred[2][2] + wred[3][2] + 1e-8f);
    float inv3 = 1.0f / (wred[0][3] + wred[1][3] + wred[2][3] + wred[3][3] + 1e-8f);

    const float* inc_b = incoming + (size_t)b * NN * DD;
    float c0 = 0, c1 = 0, c2 = 0, c3 = 0;
    #pragma unroll 4
    for (int m = 0; m < NN; ++m) {
        float v = inc_b[(size_t)m * DD + t];
        float4 ww = w4[m];
        c0 = fmaf(ww.x, v, c0); c1 = fmaf(ww.y, v, c1);
        c2 = fmaf(ww.z, v, c2); c3 = fmaf(ww.w, v, c3);
    }
    float comb[4] = { c0 * inv0, c1 * inv1, c2 * inv2, c3 * inv3 };
    #pragma unroll
    for (int r = 0; r < 4; ++r) {
        float incv = inc_b[(size_t)(n0 + r) * DD + t];
        mixed[((size_t)b * NN + n0 + r) * DD + t] = 0.8f * incv + 0.2f * comb[r];
    }
}

// ---------------- Stage 4: HDC memory (sign-GEMM, write, cosine, recall) ----------------
// grid: BATCH*NN/8 blocks, 256 threads. Each block: 8 rows.
__global__ __launch_bounds__(256) void hdc_kernel(
    const float* __restrict__ mixed, const float* __restrict__ mem,
    const float* __restrict__ W2h, const float* __restrict__ b2h,
    const float* __restrict__ Wfh, const float* __restrict__ bfh,
    const float* __restrict__ keys, const float* __restrict__ pos_codes,
    const int* __restrict__ step, float* __restrict__ out)
{
    const int row0 = blockIdx.x * 8;     // global row index b*NN + n
    const int t = threadIdx.x;
    __shared__ float4 mx4[8][DD / 4];            // 8 KB mixed rows
    __shared__ alignas(16) float nm_lds[8][256]; // 8 KB new_mem chunk
    __shared__ float wnum[8][4], wns[8][4];
    __shared__ float strength[8];

    for (int i = t; i < 8 * (DD / 4); i += 256) {
        int r = i >> 6, d4 = i & 63;
        mx4[r][d4] = ((const float4*)(mixed + (size_t)(row0 + r) * DD))[d4];
    }
    __syncthreads();

    int st = ((step[0] % 256) + 256) % 256;
    const float* pos = pos_codes + (size_t)st * HH;

    float racc[8];
    float pnum[8], pns[8];
    #pragma unroll
    for (int r = 0; r < 8; ++r) { racc[r] = 0; pnum[r] = 0; pns[r] = 0; }

    for (int chunk = 0; chunk < 8; ++chunk) {
        const int h = chunk * 256 + t;
        float z[8];
        float bb = b2h[h];
        #pragma unroll
        for (int r = 0; r < 8; ++r) z[r] = bb;
        for (int d4 = 0; d4 < DD / 4; ++d4) {
            float w0 = W2h[(size_t)(4 * d4 + 0) * HH + h];
            float w1 = W2h[(size_t)(4 * d4 + 1) * HH + h];
            float w2 = W2h[(size_t)(4 * d4 + 2) * HH + h];
            float w3 = W2h[(size_t)(4 * d4 + 3) * HH + h];
            #pragma unroll
            for (int r = 0; r < 8; ++r) {
                float4 mv = mx4[r][d4];
                z[r] = fmaf(mv.x, w0, fmaf(mv.y, w1, fmaf(mv.z, w2, fmaf(mv.w, w3, z[r]))));
            }
        }
        float posv = pos[h];
        #pragma unroll
        for (int r = 0; r < 8; ++r) {
            float qv = (z[r] >= 0.0f) ? 1.0f : -1.0f;   // sign with 0 -> +1 (STE fwd)
            int n = (row0 + r) & (NN - 1);
            float keyv = keys[(size_t)n * HH + h];
            float memv = mem[(size_t)(row0 + r) * HH + h];
            float nmv = 0.95f * memv + 0.05f * qv * posv;
            float pqv = qv * keyv;
            pnum[r] = fmaf(nmv, pqv, pnum[r]);
            pns[r]  = fmaf(nmv, nmv, pns[r]);
            nm_lds[r][t] = nmv;
        }
        __syncthreads();
        // recall partial: out_d += new_mem[h] * Wfh[h, d], d = t
        for (int hh4 = 0; hh4 < 64; ++hh4) {
            int hb = chunk * 256 + 4 * hh4;
            float w0 = Wfh[(size_t)(hb + 0) * DD + t];
            float w1 = Wfh[(size_t)(hb + 1) * DD + t];
            float w2 = Wfh[(size_t)(hb + 2) * DD + t];
            float w3 = Wfh[(size_t)(hb + 3) * DD + t];
            #pragma unroll
            for (int r = 0; r < 8; ++r) {
                float4 nv = ((const float4*)nm_lds[r])[hh4];
                racc[r] = fmaf(nv.x, w0, fmaf(nv.y, w1, fmaf(nv.z, w2, fmaf(nv.w, w3, racc[r]))));
            }
        }
        __syncthreads();
    }

    int lane = t & 63, wid = t >> 6;
    #pragma unroll
    for (int r = 0; r < 8; ++r) {
        float a = pnum[r], bb = pns[r];
        #pragma unroll
        for (int off = 32; off; off >>= 1) { a += __shfl_xor(a, off); bb += __shfl_xor(bb, off); }
        if (lane == 0) { wnum[r][wid] = a; wns[r][wid] = bb; }
    }
    __syncthreads();
    if (t < 8) {
        int r = t;
        float num = wnum[r][0] + wnum[r][1] + wnum[r][2] + wnum[r][3];
        float ns  = wns[r][0] + wns[r][1] + wns[r][2] + wns[r][3];
        float na = fmaxf(sqrtf(ns), 1e-8f);
        float nb = sqrtf(2048.0f);           // ||pq|| exactly (pq is +-1)
        float cosv = num / (na * nb);
        strength[r] = 1.0f / (1.0f + expf(-cosv));
    }
    __syncthreads();

    float bfv = bfh[t];
    #pragma unroll
    for (int r = 0; r < 8; ++r) {
        float mval = ((const float*)mx4[r])[t];
        out[(size_t)(row0 + r) * DD + t] = mval + (racc[r] + bfv) * strength[r];
    }
}

extern "C" void kernel_launch(void* const* d_in, const int* in_sizes, int n_in,
                              void* d_out, int out_size, void* d_ws, size_t ws_size,
                              hipStream_t stream) {
    const float* states    = (const float*)d_in[0];
    const float* actions   = (const float*)d_in[1];
    const float* mem       = (const float*)d_in[2];
    const float* Wq        = (const float*)d_in[3];
    const float* bq        = (const float*)d_in[4];
    const float* Wk        = (const float*)d_in[5];
    const float* bk        = (const float*)d_in[6];
    const float* log_temp  = (const float*)d_in[7];
    const float* Wc        = (const float*)d_in[8];
    const float* bc        = (const float*)d_in[9];
    const float* temp_coal = (const float*)d_in[10];
    const float* W2h       = (const float*)d_in[11];
    const float* b2h       = (const float*)d_in[12];
    const float* Wfh       = (const float*)d_in[13];
    const float* bfh       = (const float*)d_in[14];
    const float* keys      = (const float*)d_in[15];
    const float* pos_codes = (const float*)d_in[16];
    const int*   step      = (const int*)d_in[17];
    float* out = (float*)d_out;

    float* ws = (float*)d_ws;
    float* Q        = ws;
    float* K        = Q  + (size_t)BATCH * NN * DP;
    float* pn       = K  + (size_t)BATCH * NN * DP;
    float* incoming = pn + (size_t)BATCH * NN * DP;
    float* mixed    = incoming + (size_t)BATCH * NN * DD;

    proj_kernel<<<BATCH * NN / 4, 64, 0, stream>>>(actions, Wq, bq, Wk, bk, Wc, bc, Q, K, pn);
    attn_kernel<<<BATCH * NN, 256, 0, stream>>>(Q, K, states, log_temp, incoming);
    coal_kernel<<<BATCH * (NN / 4), 256, 0, stream>>>(pn, incoming, temp_coal, mixed);
    hdc_kernel<<<BATCH * NN / 8, 256, 0, stream>>>(mixed, mem, W2h, b2h, Wfh, bfh,
                                                   keys, pos_codes, step, out);
}

// Round 2
// 1378.303 us; speedup vs baseline: 1.6082x; 1.6082x over previous
//
#include <hip/hip_runtime.h>
#include <math.h>

#define BATCH 4
#define NN 2048
#define DD 256
#define HH 2048
#define DP 64
#define KTOP 16

typedef float f32x4 __attribute__((ext_vector_type(4)));
typedef short short8 __attribute__((ext_vector_type(8)));

__device__ __forceinline__ short f2bf(float x) {
    union { float f; unsigned u; } v; v.f = x;
    unsigned r = v.u + 0x7FFFu + ((v.u >> 16) & 1u);   // round-to-nearest-even
    return (short)(r >> 16);
}
__device__ __forceinline__ float bf2f(short s) {
    union { unsigned u; float f; } v; v.u = ((unsigned)(unsigned short)s) << 16;
    return v.f;
}

// ---------------- Stage 1: Q/K/proj projections + pn normalize (pn -> bf16) ----------------
__global__ __launch_bounds__(64) void proj_kernel(
    const float* __restrict__ act,
    const float* __restrict__ Wq, const float* __restrict__ bq,
    const float* __restrict__ Wk, const float* __restrict__ bk,
    const float* __restrict__ Wc, const float* __restrict__ bc,
    float* __restrict__ Qo, float* __restrict__ Ko, short* __restrict__ Pno)
{
    const int row0 = blockIdx.x * 4;
    const int t = threadIdx.x;
    __shared__ float rowbuf[4][DD];
    const float* src = act + (size_t)row0 * DD;
    for (int i = t; i < 4 * DD; i += 64) rowbuf[i >> 8][i & 255] = src[i];
    __syncthreads();

    float q[4], k[4], c[4];
    #pragma unroll
    for (int r = 0; r < 4; ++r) { q[r] = bq[t]; k[r] = bk[t]; c[r] = bc[t]; }

    for (int d = 0; d < DD; ++d) {
        float wq = Wq[d * DP + t];
        float wk = Wk[d * DP + t];
        float wc = Wc[d * DP + t];
        #pragma unroll
        for (int r = 0; r < 4; ++r) {
            float av = rowbuf[r][d];
            q[r] = fmaf(av, wq, q[r]);
            k[r] = fmaf(av, wk, k[r]);
            c[r] = fmaf(av, wc, c[r]);
        }
    }
    #pragma unroll
    for (int r = 0; r < 4; ++r) {
        float ss = c[r] * c[r];
        #pragma unroll
        for (int off = 32; off; off >>= 1) ss += __shfl_xor(ss, off);
        float nrm = fmaxf(sqrtf(ss), 1e-12f);
        size_t o = (size_t)(row0 + r) * DP + t;
        Qo[o] = q[r];
        Ko[o] = k[r];
        Pno[o] = f2bf(c[r] / nrm);
    }
}

// ---------------- Stage 2: scores + top-16 + softmax + sparse incoming ----------------
__global__ __launch_bounds__(256) void attn_kernel(
    const float* __restrict__ Q, const float* __restrict__ K,
    const float* __restrict__ states, const float* __restrict__ log_temp,
    float* __restrict__ incoming)
{
    const int row = blockIdx.x;        // b*NN + n
    const int b = row >> 11;
    const int t = threadIdx.x;
    __shared__ alignas(16) float qrow[DP];
    __shared__ float s[NN];
    __shared__ float rv[256];
    __shared__ int   ri[256];
    __shared__ float selw[KTOP];
    __shared__ int   seli[KTOP];
    __shared__ float invZ_sh;

    if (t < DP) qrow[t] = Q[(size_t)row * DP + t];
    __syncthreads();

    float temp = fminf(fmaxf(expf(log_temp[0]), 0.1f), 10.0f);
    float scale = 1.0f / (8.0f * temp);   // SCALE = sqrt(64) = 8

    const float* Kb = K + (size_t)b * NN * DP;
    for (int m = t; m < NN; m += 256) {
        const float4* kr = (const float4*)(Kb + (size_t)m * DP);
        const float4* qr = (const float4*)qrow;
        float acc = 0.0f;
        #pragma unroll
        for (int d4 = 0; d4 < 16; ++d4) {
            float4 kv = kr[d4];
            float4 qv = qr[d4];
            acc = fmaf(kv.x, qv.x, fmaf(kv.y, qv.y, fmaf(kv.z, qv.z, fmaf(kv.w, qv.w, acc))));
        }
        s[m] = acc * scale;
    }
    __syncthreads();

    for (int it = 0; it < KTOP; ++it) {
        float bv = -INFINITY; int bi = 0x7FFFFFFF;
        for (int m = t; m < NN; m += 256) {
            float v = s[m];
            if (v > bv || (v == bv && m < bi)) { bv = v; bi = m; }
        }
        rv[t] = bv; ri[t] = bi;
        __syncthreads();
        for (int off = 128; off; off >>= 1) {
            if (t < off) {
                float v2 = rv[t + off]; int i2 = ri[t + off];
                if (v2 > rv[t] || (v2 == rv[t] && i2 < ri[t])) { rv[t] = v2; ri[t] = i2; }
            }
            __syncthreads();
        }
        if (t == 0) { selw[it] = rv[0]; seli[it] = ri[0]; s[ri[0]] = -INFINITY; }
        __syncthreads();
    }
    if (t == 0) {
        float mx = selw[0];
        float Z = 0.0f;
        for (int i = 0; i < KTOP; ++i) { float w = expf(selw[i] - mx); selw[i] = w; Z += w; }
        invZ_sh = 1.0f / Z;
    }
    __syncthreads();

    const float* Sb = states + (size_t)b * NN * DD;
    float invZ = invZ_sh;
    float acc = 0.0f;
    #pragma unroll 4
    for (int kk = 0; kk < KTOP; ++kk)
        acc = fmaf(selw[kk], Sb[(size_t)seli[kk] * DD + t], acc);
    incoming[(size_t)row * DD + t] = acc * invZ;
}

// ---------------- Stage 3 (MFMA): sim -> sigmoid -> normalize -> combined -> mixed ----------------
// grid: BATCH * (NN/32) * 2 blocks, 256 threads (4 waves).
// Each block: 32 output rows x 128 output cols (d-half), K-loop over 2048 m in chunks of 64.
__global__ __launch_bounds__(256) void coal_kernel(
    const short* __restrict__ pnb_g, const float* __restrict__ incoming,
    const float* __restrict__ temp_coal, float* __restrict__ mixed)
{
    const int b  = blockIdx.x >> 7;
    const int rem = blockIdx.x & 127;
    const int n0 = (rem >> 1) * 32;
    const int dh = rem & 1;                 // d half: 0 or 1
    const int t = threadIdx.x;
    const int w = t >> 6;                   // wave 0..3
    const int l = t & 63;                   // lane

    __shared__ alignas(16) short pnA[32][72];    // block's 32 pn rows
    __shared__ alignas(16) short pnB[64][72];    // chunk's 64 pn rows
    __shared__ alignas(16) short cwt[32][72];    // sigmoid weights tile (bf16)
    __shared__ alignas(16) short incT[128][72];  // transposed incoming chunk (d-major)
    __shared__ float rowsum[32];

    const size_t bbase = (size_t)b * NN;

    // load pnA once: 32 rows x 64 k
    {
        int r = t >> 3, k8 = (t & 7) * 8;
        *(short8*)&pnA[r][k8] = *(const short8*)(pnb_g + (bbase + n0 + r) * DP + k8);
    }
    if (t < 32) rowsum[t] = 0.0f;

    const float tc = temp_coal[0];

    f32x4 acc[2][2];
    #pragma unroll
    for (int i = 0; i < 2; ++i)
        #pragma unroll
        for (int j = 0; j < 2; ++j)
            acc[i][j] = (f32x4){0.f, 0.f, 0.f, 0.f};

    const int lrow = l & 15;     // fragment row/col index
    const int lk   = (l >> 4) * 8;

    for (int ch = 0; ch < 32; ++ch) {
        const int m0 = ch * 64;
        __syncthreads();   // previous gemm2 done reading pnB/incT/cwt

        // stage pnB: 64 rows x 64 k (bf16)
        {
            int r = t >> 2, kq = (t & 3) * 16;
            const short* src = pnb_g + (bbase + m0 + r) * DP + kq;
            *(short8*)&pnB[r][kq]     = *(const short8*)src;
            *(short8*)&pnB[r][kq + 8] = *(const short8*)(src + 8);
        }
        // stage incT: transpose incoming[m0..m0+64][dh*128..+128] -> incT[d][m] bf16
        {
            int d4 = t & 31;        // float4 index along d (128 floats)
            int mg = t >> 5;        // 0..7, 8 m's each
            const float* incb = incoming + (bbase + m0) * DD + dh * 128 + d4 * 4;
            #pragma unroll
            for (int i = 0; i < 8; ++i) {
                int m = mg * 8 + i;
                float4 v = *(const float4*)(incb + (size_t)m * DD);
                int db = d4 * 4;
                incT[db + 0][m] = f2bf(v.x);
                incT[db + 1][m] = f2bf(v.y);
                incT[db + 2][m] = f2bf(v.z);
                incT[db + 3][m] = f2bf(v.w);
            }
        }
        __syncthreads();   // staging complete

        // sim = pnA(32 rows) @ pnB(64 cols)^T ; wave w computes cols w*16..w*16+16
        f32x4 sacc[2];
        sacc[0] = (f32x4){0.f, 0.f, 0.f, 0.f};
        sacc[1] = (f32x4){0.f, 0.f, 0.f, 0.f};
        #pragma unroll
        for (int ks = 0; ks < 2; ++ks) {
            short8 bfr = *(const short8*)&pnB[w * 16 + lrow][lk + ks * 32];
            short8 a0  = *(const short8*)&pnA[lrow][lk + ks * 32];
            short8 a1  = *(const short8*)&pnA[16 + lrow][lk + ks * 32];
            sacc[0] = __builtin_amdgcn_mfma_f32_16x16x32_bf16(a0, bfr, sacc[0], 0, 0, 0);
            sacc[1] = __builtin_amdgcn_mfma_f32_16x16x32_bf16(a1, bfr, sacc[1], 0, 0, 0);
        }
        // sigmoid -> cw tile (bf16). D layout: col = l&15, row = (l>>4)*4 + j
        #pragma unroll
        for (int rt = 0; rt < 2; ++rt) {
            #pragma unroll
            for (int j = 0; j < 4; ++j) {
                int row = rt * 16 + (l >> 4) * 4 + j;
                int col = w * 16 + lrow;
                float cv = 1.0f / (1.0f + expf(-(sacc[rt][j] - 0.7f) * tc));
                cwt[row][col] = f2bf(cv);
            }
        }
        __syncthreads();   // cw tile visible

        // rowsum partial: 8 threads per row, 8 cols each
        {
            int r = t >> 3, c8 = (t & 7) * 8;
            short8 cv = *(const short8*)&cwt[r][c8];
            float p = 0.f;
            #pragma unroll
            for (int j = 0; j < 8; ++j) p += bf2f(cv[j]);
            p += __shfl_xor(p, 1);
            p += __shfl_xor(p, 2);
            p += __shfl_xor(p, 4);
            if ((t & 7) == 0) rowsum[r] += p;
        }

        // gemm2: combined += cw(32 x 64) @ incT^T ; wave w -> cols w*32..w*32+32
        #pragma unroll
        for (int ks = 0; ks < 2; ++ks) {
            short8 a0 = *(const short8*)&cwt[lrow][lk + ks * 32];
            short8 a1 = *(const short8*)&cwt[16 + lrow][lk + ks * 32];
            #pragma unroll
            for (int ct = 0; ct < 2; ++ct) {
                short8 bfr = *(const short8*)&incT[w * 32 + ct * 16 + lrow][lk + ks * 32];
                acc[0][ct] = __builtin_amdgcn_mfma_f32_16x16x32_bf16(a0, bfr, acc[0][ct], 0, 0, 0);
                acc[1][ct] = __builtin_amdgcn_mfma_f32_16x16x32_bf16(a1, bfr, acc[1][ct], 0, 0, 0);
            }
        }
    }
    __syncthreads();   // final rowsum visible

    #pragma unroll
    for (int rt = 0; rt < 2; ++rt) {
        #pragma unroll
        for (int ct = 0; ct < 2; ++ct) {
            #pragma unroll
            for (int j = 0; j < 4; ++j) {
                int row = rt * 16 + (l >> 4) * 4 + j;
                int col = w * 32 + ct * 16 + lrow;
                float inv = 1.0f / (rowsum[row] + 1e-8f);
                float comb = acc[rt][ct][j] * inv;
                size_t gi = (bbase + n0 + row) * DD + dh * 128 + col;
                mixed[gi] = 0.8f * incoming[gi] + 0.2f * comb;
            }
        }
    }
}

// ---------------- Stage 4: HDC memory (sign-GEMM, write, cosine, recall) ----------------
__global__ __launch_bounds__(256) void hdc_kernel(
    const float* __restrict__ mixed, const float* __restrict__ mem,
    const float* __restrict__ W2h, const float* __restrict__ b2h,
    const float* __restrict__ Wfh, const float* __restrict__ bfh,
    const float* __restrict__ keys, const float* __restrict__ pos_codes,
    const int* __restrict__ step, float* __restrict__ out)
{
    const int row0 = blockIdx.x * 8;
    const int t = threadIdx.x;
    __shared__ float4 mx4[8][DD / 4];
    __shared__ alignas(16) float nm_lds[8][256];
    __shared__ float wnum[8][4], wns[8][4];
    __shared__ float strength[8];

    for (int i = t; i < 8 * (DD / 4); i += 256) {
        int r = i >> 6, d4 = i & 63;
        mx4[r][d4] = ((const float4*)(mixed + (size_t)(row0 + r) * DD))[d4];
    }
    __syncthreads();

    int st = ((step[0] % 256) + 256) % 256;
    const float* pos = pos_codes + (size_t)st * HH;

    float racc[8];
    float pnum[8], pns[8];
    #pragma unroll
    for (int r = 0; r < 8; ++r) { racc[r] = 0; pnum[r] = 0; pns[r] = 0; }

    for (int chunk = 0; chunk < 8; ++chunk) {
        const int h = chunk * 256 + t;
        float z[8];
        float bb = b2h[h];
        #pragma unroll
        for (int r = 0; r < 8; ++r) z[r] = bb;
        for (int d4 = 0; d4 < DD / 4; ++d4) {
            float w0 = W2h[(size_t)(4 * d4 + 0) * HH + h];
            float w1 = W2h[(size_t)(4 * d4 + 1) * HH + h];
            float w2 = W2h[(size_t)(4 * d4 + 2) * HH + h];
            float w3 = W2h[(size_t)(4 * d4 + 3) * HH + h];
            #pragma unroll
            for (int r = 0; r < 8; ++r) {
                float4 mv = mx4[r][d4];
                z[r] = fmaf(mv.x, w0, fmaf(mv.y, w1, fmaf(mv.z, w2, fmaf(mv.w, w3, z[r]))));
            }
        }
        float posv = pos[h];
        #pragma unroll
        for (int r = 0; r < 8; ++r) {
            float qv = (z[r] >= 0.0f) ? 1.0f : -1.0f;
            int n = (row0 + r) & (NN - 1);
            float keyv = keys[(size_t)n * HH + h];
            float memv = mem[(size_t)(row0 + r) * HH + h];
            float nmv = 0.95f * memv + 0.05f * qv * posv;
            float pqv = qv * keyv;
            pnum[r] = fmaf(nmv, pqv, pnum[r]);
            pns[r]  = fmaf(nmv, nmv, pns[r]);
            nm_lds[r][t] = nmv;
        }
        __syncthreads();
        for (int hh4 = 0; hh4 < 64; ++hh4) {
            int hb = chunk * 256 + 4 * hh4;
            float w0 = Wfh[(size_t)(hb + 0) * DD + t];
            float w1 = Wfh[(size_t)(hb + 1) * DD + t];
            float w2 = Wfh[(size_t)(hb + 2) * DD + t];
            float w3 = Wfh[(size_t)(hb + 3) * DD + t];
            #pragma unroll
            for (int r = 0; r < 8; ++r) {
                float4 nv = ((const float4*)nm_lds[r])[hh4];
                racc[r] = fmaf(nv.x, w0, fmaf(nv.y, w1, fmaf(nv.z, w2, fmaf(nv.w, w3, racc[r]))));
            }
        }
        __syncthreads();
    }

    int lane = t & 63, wid = t >> 6;
    #pragma unroll
    for (int r = 0; r < 8; ++r) {
        float a = pnum[r], bb = pns[r];
        #pragma unroll
        for (int off = 32; off; off >>= 1) { a += __shfl_xor(a, off); bb += __shfl_xor(bb, off); }
        if (lane == 0) { wnum[r][wid] = a; wns[r][wid] = bb; }
    }
    __syncthreads();
    if (t < 8) {
        int r = t;
        float num = wnum[r][0] + wnum[r][1] + wnum[r][2] + wnum[r][3];
        float ns  = wns[r][0] + wns[r][1] + wns[r][2] + wns[r][3];
        float na = fmaxf(sqrtf(ns), 1e-8f);
        float nb = sqrtf(2048.0f);
        float cosv = num / (na * nb);
        strength[r] = 1.0f / (1.0f + expf(-cosv));
    }
    __syncthreads();

    float bfv = bfh[t];
    #pragma unroll
    for (int r = 0; r < 8; ++r) {
        float mval = ((const float*)mx4[r])[t];
        out[(size_t)(row0 + r) * DD + t] = mval + (racc[r] + bfv) * strength[r];
    }
}

extern "C" void kernel_launch(void* const* d_in, const int* in_sizes, int n_in,
                              void* d_out, int out_size, void* d_ws, size_t ws_size,
                              hipStream_t stream) {
    const float* states    = (const float*)d_in[0];
    const float* actions   = (const float*)d_in[1];
    const float* mem       = (const float*)d_in[2];
    const float* Wq        = (const float*)d_in[3];
    const float* bq        = (const float*)d_in[4];
    const float* Wk        = (const float*)d_in[5];
    const float* bk        = (const float*)d_in[6];
    const float* log_temp  = (const float*)d_in[7];
    const float* Wc        = (const float*)d_in[8];
    const float* bc        = (const float*)d_in[9];
    const float* temp_coal = (const float*)d_in[10];
    const float* W2h       = (const float*)d_in[11];
    const float* b2h       = (const float*)d_in[12];
    const float* Wfh       = (const float*)d_in[13];
    const float* bfh       = (const float*)d_in[14];
    const float* keys      = (const float*)d_in[15];
    const float* pos_codes = (const float*)d_in[16];
    const int*   step      = (const int*)d_in[17];
    float* out = (float*)d_out;

    float* ws = (float*)d_ws;
    float* Q        = ws;
    float* K        = Q  + (size_t)BATCH * NN * DP;
    float* incoming = K  + (size_t)BATCH * NN * DP;
    float* mixed    = incoming + (size_t)BATCH * NN * DD;
    short* pn_bf    = (short*)(mixed + (size_t)BATCH * NN * DD);

    proj_kernel<<<BATCH * NN / 4, 64, 0, stream>>>(actions, Wq, bq, Wk, bk, Wc, bc, Q, K, pn_bf);
    attn_kernel<<<BATCH * NN, 256, 0, stream>>>(Q, K, states, log_temp, incoming);
    coal_kernel<<<BATCH * (NN / 32) * 2, 256, 0, stream>>>(pn_bf, incoming, temp_coal, mixed);
    hdc_kernel<<<BATCH * NN / 8, 256, 0, stream>>>(mixed, mem, W2h, b2h, Wfh, bfh,
                                                   keys, pos_codes, step, out);
}

// Round 3
// 865.489 us; speedup vs baseline: 2.5610x; 1.5925x over previous
//
#include <hip/hip_runtime.h>
#include <math.h>

#define BATCH 4
#define NN 2048
#define DD 256
#define HH 2048
#define DP 64
#define KTOP 16

typedef float f32x4 __attribute__((ext_vector_type(4)));
typedef short short8 __attribute__((ext_vector_type(8)));

__device__ __forceinline__ short f2bf(float x) {
    union { float f; unsigned u; } v; v.f = x;
    unsigned r = v.u + 0x7FFFu + ((v.u >> 16) & 1u);   // round-to-nearest-even
    return (short)(r >> 16);
}
__device__ __forceinline__ float bf2f(short s) {
    union { unsigned u; float f; } v; v.u = ((unsigned)(unsigned short)s) << 16;
    return v.f;
}
__device__ __forceinline__ unsigned long long shfl_xor_u64(unsigned long long v, int off) {
    unsigned lo = (unsigned)v, hi = (unsigned)(v >> 32);
    lo = __shfl_xor(lo, off); hi = __shfl_xor(hi, off);
    return ((unsigned long long)hi << 32) | lo;
}

// ---------------- Stage 1: Q/K/proj projections + pn normalize (pn -> bf16) ----------------
__global__ __launch_bounds__(64) void proj_kernel(
    const float* __restrict__ act,
    const float* __restrict__ Wq, const float* __restrict__ bq,
    const float* __restrict__ Wk, const float* __restrict__ bk,
    const float* __restrict__ Wc, const float* __restrict__ bc,
    float* __restrict__ Qo, float* __restrict__ Ko, short* __restrict__ Pno)
{
    const int row0 = blockIdx.x * 4;
    const int t = threadIdx.x;
    __shared__ float rowbuf[4][DD];
    const float* src = act + (size_t)row0 * DD;
    for (int i = t; i < 4 * DD; i += 64) rowbuf[i >> 8][i & 255] = src[i];
    __syncthreads();

    float q[4], k[4], c[4];
    #pragma unroll
    for (int r = 0; r < 4; ++r) { q[r] = bq[t]; k[r] = bk[t]; c[r] = bc[t]; }

    for (int d = 0; d < DD; ++d) {
        float wq = Wq[d * DP + t];
        float wk = Wk[d * DP + t];
        float wc = Wc[d * DP + t];
        #pragma unroll
        for (int r = 0; r < 4; ++r) {
            float av = rowbuf[r][d];
            q[r] = fmaf(av, wq, q[r]);
            k[r] = fmaf(av, wk, k[r]);
            c[r] = fmaf(av, wc, c[r]);
        }
    }
    #pragma unroll
    for (int r = 0; r < 4; ++r) {
        float ss = c[r] * c[r];
        #pragma unroll
        for (int off = 32; off; off >>= 1) ss += __shfl_xor(ss, off);
        float nrm = fmaxf(sqrtf(ss), 1e-12f);
        size_t o = (size_t)(row0 + r) * DP + t;
        Qo[o] = q[r];
        Ko[o] = k[r];
        Pno[o] = f2bf(c[r] / nrm);
    }
}

// ---------------- Prep: transpose + bf16 hi/lo split of W2h and Wfh ----------------
__global__ __launch_bounds__(256) void prep_kernel(
    const float* __restrict__ W2h, const float* __restrict__ Wfh,
    short* __restrict__ W2hT_hi, short* __restrict__ W2hT_lo,
    short* __restrict__ WfhT_hi, short* __restrict__ WfhT_lo)
{
    int b = blockIdx.x;
    const float* src; short *dhi, *dlo; int R, C, r0, c0;
    if (b < 512) {               // W2h [256][2048] -> W2hT [2048][256]
        src = W2h; dhi = W2hT_hi; dlo = W2hT_lo; R = 256; C = 2048;
        r0 = (b >> 6) * 32; c0 = (b & 63) * 32;
    } else {                     // Wfh [2048][256] -> WfhT [256][2048]
        b -= 512;
        src = Wfh; dhi = WfhT_hi; dlo = WfhT_lo; R = 2048; C = 256;
        r0 = (b >> 3) * 32; c0 = (b & 7) * 32;
    }
    int tx = threadIdx.x & 31, ty = threadIdx.x >> 5;
    __shared__ float tile[32][33];
    #pragma unroll
    for (int i = 0; i < 4; ++i)
        tile[ty + 8 * i][tx] = src[(size_t)(r0 + ty + 8 * i) * C + c0 + tx];
    __syncthreads();
    #pragma unroll
    for (int i = 0; i < 4; ++i) {
        float v = tile[tx][ty + 8 * i];
        short hi = f2bf(v);
        size_t o = (size_t)(c0 + ty + 8 * i) * R + r0 + tx;
        dhi[o] = hi;
        dlo[o] = f2bf(v - bf2f(hi));
    }
}

// ---------------- Stage 2: scores + wave-register top-16 + softmax + sparse incoming ----------------
__global__ __launch_bounds__(256) void attn_kernel(
    const float* __restrict__ Q, const float* __restrict__ K,
    const float* __restrict__ states, const float* __restrict__ log_temp,
    float* __restrict__ incoming)
{
    const int row = blockIdx.x;        // b*NN + n
    const int b = row >> 11;
    const int t = threadIdx.x;
    const int w = t >> 6, l = t & 63;
    __shared__ alignas(16) float qrow[DP];
    __shared__ float s[NN];
    __shared__ unsigned long long topk[4][KTOP];
    __shared__ float selw[KTOP];
    __shared__ int   seli[KTOP];
    __shared__ float invZ_sh;

    if (t < DP) qrow[t] = Q[(size_t)row * DP + t];
    __syncthreads();

    float temp = fminf(fmaxf(expf(log_temp[0]), 0.1f), 10.0f);
    float scale = 1.0f / (8.0f * temp);   // SCALE = sqrt(64) = 8

    const float* Kb = K + (size_t)b * NN * DP;
    for (int m = t; m < NN; m += 256) {
        const float4* kr = (const float4*)(Kb + (size_t)m * DP);
        const float4* qr = (const float4*)qrow;
        float acc = 0.0f;
        #pragma unroll
        for (int d4 = 0; d4 < 16; ++d4) {
            float4 kv = kr[d4];
            float4 qv = qr[d4];
            acc = fmaf(kv.x, qv.x, fmaf(kv.y, qv.y, fmaf(kv.z, qv.z, fmaf(kv.w, qv.w, acc))));
        }
        s[m] = acc * scale;
    }
    __syncthreads();

    // per-wave top-16 tournament on sortable u64 keys (value bits || ~index)
    unsigned long long key[8];
    #pragma unroll
    for (int i = 0; i < 8; ++i) {
        int m = w * 512 + i * 64 + l;
        unsigned bb = __float_as_uint(s[m]);
        unsigned u = bb ^ (unsigned)(((int)bb >> 31) | 0x80000000);
        key[i] = ((unsigned long long)u << 32) | (unsigned)(~m);
    }
    for (int it = 0; it < KTOP; ++it) {
        unsigned long long best = key[0];
        #pragma unroll
        for (int i = 1; i < 8; ++i) best = key[i] > best ? key[i] : best;
        #pragma unroll
        for (int off = 1; off < 64; off <<= 1) {
            unsigned long long o = shfl_xor_u64(best, off);
            best = o > best ? o : best;
        }
        #pragma unroll
        for (int i = 0; i < 8; ++i) if (key[i] == best) key[i] = 0;
        if (l == 0) topk[w][it] = best;
    }
    __syncthreads();
    if (w == 0) {
        unsigned long long c = topk[l >> 4][l & 15];
        for (int it = 0; it < KTOP; ++it) {
            unsigned long long best = c;
            #pragma unroll
            for (int off = 1; off < 64; off <<= 1) {
                unsigned long long o = shfl_xor_u64(best, off);
                best = o > best ? o : best;
            }
            if (c == best) c = 0;
            if (l == 0) {
                unsigned u = (unsigned)(best >> 32);
                unsigned bb = (u & 0x80000000u) ? (u ^ 0x80000000u) : ~u;
                selw[it] = __uint_as_float(bb);
                seli[it] = (int)((~(unsigned)best) & (NN - 1));
            }
        }
        if (l == 0) {
            float mx = selw[0], Z = 0.0f;
            for (int i = 0; i < KTOP; ++i) { float e = expf(selw[i] - mx); selw[i] = e; Z += e; }
            invZ_sh = 1.0f / Z;
        }
    }
    __syncthreads();

    const float* Sb = states + (size_t)b * NN * DD;
    float invZ = invZ_sh;
    float acc = 0.0f;
    #pragma unroll 4
    for (int kk = 0; kk < KTOP; ++kk)
        acc = fmaf(selw[kk], Sb[(size_t)seli[kk] * DD + t], acc);
    incoming[(size_t)row * DD + t] = acc * invZ;
}

// ---------------- Stage 3 (MFMA): sim -> sigmoid -> normalize -> combined -> mixed ----------------
__global__ __launch_bounds__(256) void coal_kernel(
    const short* __restrict__ pnb_g, const float* __restrict__ incoming,
    const float* __restrict__ temp_coal, float* __restrict__ mixed)
{
    const int b  = blockIdx.x >> 7;
    const int rem = blockIdx.x & 127;
    const int n0 = (rem >> 1) * 32;
    const int dh = rem & 1;
    const int t = threadIdx.x;
    const int w = t >> 6;
    const int l = t & 63;

    __shared__ alignas(16) short pnA[32][72];
    __shared__ alignas(16) short pnB[64][72];
    __shared__ alignas(16) short cwt[32][72];
    __shared__ alignas(16) short incT[128][72];
    __shared__ float rowsum[32];

    const size_t bbase = (size_t)b * NN;

    {
        int r = t >> 3, k8 = (t & 7) * 8;
        *(short8*)&pnA[r][k8] = *(const short8*)(pnb_g + (bbase + n0 + r) * DP + k8);
    }
    if (t < 32) rowsum[t] = 0.0f;

    const float tc = temp_coal[0];

    f32x4 acc[2][2];
    #pragma unroll
    for (int i = 0; i < 2; ++i)
        #pragma unroll
        for (int j = 0; j < 2; ++j)
            acc[i][j] = (f32x4){0.f, 0.f, 0.f, 0.f};

    const int lrow = l & 15;
    const int lk   = (l >> 4) * 8;

    for (int ch = 0; ch < 32; ++ch) {
        const int m0 = ch * 64;
        __syncthreads();

        {
            int r = t >> 2, kq = (t & 3) * 16;
            const short* src = pnb_g + (bbase + m0 + r) * DP + kq;
            *(short8*)&pnB[r][kq]     = *(const short8*)src;
            *(short8*)&pnB[r][kq + 8] = *(const short8*)(src + 8);
        }
        {
            int d4 = t & 31;
            int mg = t >> 5;
            const float* incb = incoming + (bbase + m0) * DD + dh * 128 + d4 * 4;
            #pragma unroll
            for (int i = 0; i < 8; ++i) {
                int m = mg * 8 + i;
                float4 v = *(const float4*)(incb + (size_t)m * DD);
                int db = d4 * 4;
                incT[db + 0][m] = f2bf(v.x);
                incT[db + 1][m] = f2bf(v.y);
                incT[db + 2][m] = f2bf(v.z);
                incT[db + 3][m] = f2bf(v.w);
            }
        }
        __syncthreads();

        f32x4 sacc[2];
        sacc[0] = (f32x4){0.f, 0.f, 0.f, 0.f};
        sacc[1] = (f32x4){0.f, 0.f, 0.f, 0.f};
        #pragma unroll
        for (int ks = 0; ks < 2; ++ks) {
            short8 bfr = *(const short8*)&pnB[w * 16 + lrow][lk + ks * 32];
            short8 a0  = *(const short8*)&pnA[lrow][lk + ks * 32];
            short8 a1  = *(const short8*)&pnA[16 + lrow][lk + ks * 32];
            sacc[0] = __builtin_amdgcn_mfma_f32_16x16x32_bf16(a0, bfr, sacc[0], 0, 0, 0);
            sacc[1] = __builtin_amdgcn_mfma_f32_16x16x32_bf16(a1, bfr, sacc[1], 0, 0, 0);
        }
        #pragma unroll
        for (int rt = 0; rt < 2; ++rt) {
            #pragma unroll
            for (int j = 0; j < 4; ++j) {
                int rr = rt * 16 + (l >> 4) * 4 + j;
                int cc = w * 16 + lrow;
                float cv = 1.0f / (1.0f + expf(-(sacc[rt][j] - 0.7f) * tc));
                cwt[rr][cc] = f2bf(cv);
            }
        }
        __syncthreads();

        {
            int r = t >> 3, c8 = (t & 7) * 8;
            short8 cv = *(const short8*)&cwt[r][c8];
            float p = 0.f;
            #pragma unroll
            for (int j = 0; j < 8; ++j) p += bf2f(cv[j]);
            p += __shfl_xor(p, 1);
            p += __shfl_xor(p, 2);
            p += __shfl_xor(p, 4);
            if ((t & 7) == 0) rowsum[r] += p;
        }

        #pragma unroll
        for (int ks = 0; ks < 2; ++ks) {
            short8 a0 = *(const short8*)&cwt[lrow][lk + ks * 32];
            short8 a1 = *(const short8*)&cwt[16 + lrow][lk + ks * 32];
            #pragma unroll
            for (int ct = 0; ct < 2; ++ct) {
                short8 bfr = *(const short8*)&incT[w * 32 + ct * 16 + lrow][lk + ks * 32];
                acc[0][ct] = __builtin_amdgcn_mfma_f32_16x16x32_bf16(a0, bfr, acc[0][ct], 0, 0, 0);
                acc[1][ct] = __builtin_amdgcn_mfma_f32_16x16x32_bf16(a1, bfr, acc[1][ct], 0, 0, 0);
            }
        }
    }
    __syncthreads();

    #pragma unroll
    for (int rt = 0; rt < 2; ++rt) {
        #pragma unroll
        for (int ct = 0; ct < 2; ++ct) {
            #pragma unroll
            for (int j = 0; j < 4; ++j) {
                int rr = rt * 16 + (l >> 4) * 4 + j;
                int cc = w * 32 + ct * 16 + lrow;
                float inv = 1.0f / (rowsum[rr] + 1e-8f);
                float comb = acc[rt][ct][j] * inv;
                size_t gi = (bbase + n0 + rr) * DD + dh * 128 + cc;
                mixed[gi] = 0.8f * incoming[gi] + 0.2f * comb;
            }
        }
    }
}

// ---------------- Stage 4a (MFMA): z = mixed@W2h + b2h -> q bits, strength ----------------
// grid: 8192/32 = 256 blocks, 256 threads (4 waves). 3-term bf16 split (~fp32 exact).
#define PADA 264
#define PADW 136
__global__ __launch_bounds__(256) void hdcA_kernel(
    const float* __restrict__ mixed, const float* __restrict__ mem,
    const short* __restrict__ W2hT_hi, const short* __restrict__ W2hT_lo,
    const float* __restrict__ b2h,
    const float* __restrict__ keys, const float* __restrict__ pos_codes,
    const int* __restrict__ step,
    unsigned short* __restrict__ qbits, float* __restrict__ strength)
{
    const int row0 = blockIdx.x * 32;
    const int t = threadIdx.x;
    const int w = t >> 6, l = t & 63;
    const int lr = l & 15, lg = l >> 4;

    __shared__ short Ahi[32][PADA], Alo[32][PADA];
    __shared__ short Whi[64][PADW], Wlo[64][PADW];
    __shared__ float redN[32][4], redS[32][4];

    for (int idx = t; idx < 32 * 256; idx += 256) {
        int r = idx >> 8, c = idx & 255;
        float v = mixed[(size_t)(row0 + r) * DD + c];
        short hi = f2bf(v);
        Ahi[r][c] = hi;
        Alo[r][c] = f2bf(v - bf2f(hi));
    }

    int st = ((step[0] % 256) + 256) % 256;
    const float* pos = pos_codes + (size_t)st * HH;

    float num8[8], ns8[8];
    #pragma unroll
    for (int i = 0; i < 8; ++i) { num8[i] = 0.f; ns8[i] = 0.f; }

    for (int ch = 0; ch < 32; ++ch) {
        const int h0 = ch * 64;
        f32x4 zac[2];
        zac[0] = (f32x4){0.f, 0.f, 0.f, 0.f};
        zac[1] = (f32x4){0.f, 0.f, 0.f, 0.f};
        for (int ks = 0; ks < 2; ++ks) {
            const int k0 = ks * 128;
            __syncthreads();
            {
                int r = t >> 2, cb = (t & 3) * 32;
                const short* sh = W2hT_hi + (size_t)(h0 + r) * DD + k0 + cb;
                const short* sl = W2hT_lo + (size_t)(h0 + r) * DD + k0 + cb;
                #pragma unroll
                for (int j = 0; j < 4; ++j) {
                    *(short8*)&Whi[r][cb + j * 8] = *(const short8*)(sh + j * 8);
                    *(short8*)&Wlo[r][cb + j * 8] = *(const short8*)(sl + j * 8);
                }
            }
            __syncthreads();
            #pragma unroll
            for (int kt = 0; kt < 4; ++kt) {
                int kk = k0 + kt * 32 + lg * 8;
                int kw = kt * 32 + lg * 8;
                short8 bhi = *(const short8*)&Whi[w * 16 + lr][kw];
                short8 blo = *(const short8*)&Wlo[w * 16 + lr][kw];
                #pragma unroll
                for (int mt = 0; mt < 2; ++mt) {
                    short8 ahi = *(const short8*)&Ahi[mt * 16 + lr][kk];
                    short8 alo = *(const short8*)&Alo[mt * 16 + lr][kk];
                    zac[mt] = __builtin_amdgcn_mfma_f32_16x16x32_bf16(ahi, bhi, zac[mt], 0, 0, 0);
                    zac[mt] = __builtin_amdgcn_mfma_f32_16x16x32_bf16(ahi, blo, zac[mt], 0, 0, 0);
                    zac[mt] = __builtin_amdgcn_mfma_f32_16x16x32_bf16(alo, bhi, zac[mt], 0, 0, 0);
                }
            }
        }
        const int h = h0 + w * 16 + lr;
        const float bv = b2h[h], pv = pos[h];
        #pragma unroll
        for (int mt = 0; mt < 2; ++mt) {
            #pragma unroll
            for (int j = 0; j < 4; ++j) {
                int row = row0 + mt * 16 + lg * 4 + j;
                float z = zac[mt][j] + bv;
                float q = (z >= 0.f) ? 1.f : -1.f;
                unsigned long long bal = __ballot(z >= 0.f);
                if (lr == 0)
                    qbits[(size_t)row * 128 + (h0 >> 4) + w] =
                        (unsigned short)((bal >> (lg * 16)) & 0xFFFFull);
                float nmv = 0.95f * mem[(size_t)row * HH + h] + 0.05f * q * pv;
                float pq = q * keys[(size_t)(row & (NN - 1)) * HH + h];
                num8[mt * 4 + j] = fmaf(nmv, pq, num8[mt * 4 + j]);
                ns8[mt * 4 + j]  = fmaf(nmv, nmv, ns8[mt * 4 + j]);
            }
        }
    }

    #pragma unroll
    for (int i = 0; i < 8; ++i) {
        #pragma unroll
        for (int off = 1; off < 16; off <<= 1) {
            num8[i] += __shfl_xor(num8[i], off);
            ns8[i]  += __shfl_xor(ns8[i], off);
        }
    }
    if (lr == 0) {
        #pragma unroll
        for (int mt = 0; mt < 2; ++mt)
            #pragma unroll
            for (int j = 0; j < 4; ++j) {
                redN[mt * 16 + lg * 4 + j][w] = num8[mt * 4 + j];
                redS[mt * 16 + lg * 4 + j][w] = ns8[mt * 4 + j];
            }
    }
    __syncthreads();
    if (t < 32) {
        float num = redN[t][0] + redN[t][1] + redN[t][2] + redN[t][3];
        float ns  = redS[t][0] + redS[t][1] + redS[t][2] + redS[t][3];
        float cosv = num / (fmaxf(sqrtf(ns), 1e-8f) * sqrtf(2048.0f));
        strength[row0 + t] = 1.0f / (1.0f + expf(-cosv));
    }
}

// ---------------- Stage 4b (MFMA): recall = nm@Wfh; out = mixed + (recall+bfh)*strength ----------------
// grid: (8192/64) * 2 = 256 blocks, 256 threads (4 waves: 2m x 2n).
__global__ __launch_bounds__(256) void hdcB_kernel(
    const float* __restrict__ mem, const unsigned short* __restrict__ qbits,
    const float* __restrict__ pos_codes, const int* __restrict__ step,
    const short* __restrict__ WfhT_hi, const short* __restrict__ WfhT_lo,
    const float* __restrict__ bfh, const float* __restrict__ strength,
    const float* __restrict__ mixed, float* __restrict__ out)
{
    const int mb = blockIdx.x >> 1, nb = blockIdx.x & 1;
    const int row0 = mb * 64, d0 = nb * 128;
    const int t = threadIdx.x;
    const int w = t >> 6, l = t & 63;
    const int wm = w >> 1, wn = w & 1;
    const int lr = l & 15, lg = l >> 4;

    __shared__ short Ahi[64][72], Alo[64][72];
    __shared__ short Bhi[128][72], Blo[128][72];

    int st = ((step[0] % 256) + 256) % 256;
    const float* pos = pos_codes + (size_t)st * HH;

    f32x4 acc[2][4];
    #pragma unroll
    for (int i = 0; i < 2; ++i)
        #pragma unroll
        for (int j = 0; j < 4; ++j)
            acc[i][j] = (f32x4){0.f, 0.f, 0.f, 0.f};

    for (int kc = 0; kc < 32; ++kc) {
        const int h0 = kc * 64;
        __syncthreads();
        {   // stage A: recompute nm from mem + q bits + pos, split hi/lo
            int r = t >> 2, hb = (t & 3) * 16;
            const float* src = mem + (size_t)(row0 + r) * HH + h0 + hb;
            unsigned bits = qbits[(size_t)(row0 + r) * 128 + ((h0 + hb) >> 4)];
            #pragma unroll
            for (int j4 = 0; j4 < 4; ++j4) {
                float4 mv = *(const float4*)(src + j4 * 4);
                #pragma unroll
                for (int j = 0; j < 4; ++j) {
                    int jj = j4 * 4 + j;
                    float memv = (j == 0) ? mv.x : (j == 1) ? mv.y : (j == 2) ? mv.z : mv.w;
                    float q = (bits >> jj) & 1u ? 1.f : -1.f;
                    float nmv = 0.95f * memv + 0.05f * q * pos[h0 + hb + jj];
                    short hi = f2bf(nmv);
                    Ahi[r][hb + jj] = hi;
                    Alo[r][hb + jj] = f2bf(nmv - bf2f(hi));
                }
            }
        }
        {   // stage B: WfhT tiles
            int r = t >> 1, hb = (t & 1) * 32;
            const short* sh = WfhT_hi + (size_t)(d0 + r) * HH + h0 + hb;
            const short* sl = WfhT_lo + (size_t)(d0 + r) * HH + h0 + hb;
            #pragma unroll
            for (int j = 0; j < 4; ++j) {
                *(short8*)&Bhi[r][hb + j * 8] = *(const short8*)(sh + j * 8);
                *(short8*)&Blo[r][hb + j * 8] = *(const short8*)(sl + j * 8);
            }
        }
        __syncthreads();
        #pragma unroll
        for (int kt = 0; kt < 2; ++kt) {
            int kk = kt * 32 + lg * 8;
            #pragma unroll
            for (int mt = 0; mt < 2; ++mt) {
                short8 ahi = *(const short8*)&Ahi[wm * 32 + mt * 16 + lr][kk];
                short8 alo = *(const short8*)&Alo[wm * 32 + mt * 16 + lr][kk];
                #pragma unroll
                for (int nt = 0; nt < 4; ++nt) {
                    short8 bhi = *(const short8*)&Bhi[wn * 64 + nt * 16 + lr][kk];
                    short8 blo = *(const short8*)&Blo[wn * 64 + nt * 16 + lr][kk];
                    acc[mt][nt] = __builtin_amdgcn_mfma_f32_16x16x32_bf16(ahi, bhi, acc[mt][nt], 0, 0, 0);
                    acc[mt][nt] = __builtin_amdgcn_mfma_f32_16x16x32_bf16(ahi, blo, acc[mt][nt], 0, 0, 0);
                    acc[mt][nt] = __builtin_amdgcn_mfma_f32_16x16x32_bf16(alo, bhi, acc[mt][nt], 0, 0, 0);
                }
            }
        }
    }

    #pragma unroll
    for (int mt = 0; mt < 2; ++mt) {
        #pragma unroll
        for (int nt = 0; nt < 4; ++nt) {
            #pragma unroll
            for (int j = 0; j < 4; ++j) {
                int row = row0 + wm * 32 + mt * 16 + lg * 4 + j;
                int col = d0 + wn * 64 + nt * 16 + lr;
                float sv = strength[row];
                size_t gi = (size_t)row * DD + col;
                out[gi] = mixed[gi] + (acc[mt][nt][j] + bfh[col]) * sv;
            }
        }
    }
}

extern "C" void kernel_launch(void* const* d_in, const int* in_sizes, int n_in,
                              void* d_out, int out_size, void* d_ws, size_t ws_size,
                              hipStream_t stream) {
    const float* states    = (const float*)d_in[0];
    const float* actions   = (const float*)d_in[1];
    const float* mem       = (const float*)d_in[2];
    const float* Wq        = (const float*)d_in[3];
    const float* bq        = (const float*)d_in[4];
    const float* Wk        = (const float*)d_in[5];
    const float* bk        = (const float*)d_in[6];
    const float* log_temp  = (const float*)d_in[7];
    const float* Wc        = (const float*)d_in[8];
    const float* bc        = (const float*)d_in[9];
    const float* temp_coal = (const float*)d_in[10];
    const float* W2h       = (const float*)d_in[11];
    const float* b2h       = (const float*)d_in[12];
    const float* Wfh       = (const float*)d_in[13];
    const float* bfh       = (const float*)d_in[14];
    const float* keys      = (const float*)d_in[15];
    const float* pos_codes = (const float*)d_in[16];
    const int*   step      = (const int*)d_in[17];
    float* out = (float*)d_out;

    float* ws = (float*)d_ws;
    float* mixed    = ws;                                    // 2,097,152 f32
    short* W2hT_hi  = (short*)(mixed + 2097152);             // 524288 shorts
    short* W2hT_lo  = W2hT_hi + 524288;
    short* WfhT_hi  = W2hT_lo + 524288;
    short* WfhT_lo  = WfhT_hi + 524288;
    float* strength = (float*)(WfhT_lo + 524288);            // 8192 f32
    unsigned short* qbits = (unsigned short*)(strength + 8192);  // 1,048,576 u16
    float* Q        = (float*)(qbits + 1048576);             // 524288 f32
    float* K        = Q + 524288;
    float* incoming = K + 524288;                            // 2,097,152 f32
    short* pn_bf    = (short*)(incoming + 2097152);          // 524288 shorts

    proj_kernel<<<BATCH * NN / 4, 64, 0, stream>>>(actions, Wq, bq, Wk, bk, Wc, bc, Q, K, pn_bf);
    prep_kernel<<<1024, 256, 0, stream>>>(W2h, Wfh, W2hT_hi, W2hT_lo, WfhT_hi, WfhT_lo);
    attn_kernel<<<BATCH * NN, 256, 0, stream>>>(Q, K, states, log_temp, incoming);
    coal_kernel<<<BATCH * (NN / 32) * 2, 256, 0, stream>>>(pn_bf, incoming, temp_coal, mixed);
    hdcA_kernel<<<BATCH * NN / 32, 256, 0, stream>>>(mixed, mem, W2hT_hi, W2hT_lo, b2h,
                                                     keys, pos_codes, step, qbits, strength);
    hdcB_kernel<<<(BATCH * NN / 64) * 2, 256, 0, stream>>>(mem, qbits, pos_codes, step,
                                                           WfhT_hi, WfhT_lo, bfh, strength,
                                                           mixed, out);
}

// Round 4
// 430.123 us; speedup vs baseline: 5.1533x; 2.0122x over previous
//
#include <hip/hip_runtime.h>
#include <math.h>

#define BATCH 4
#define NN 2048
#define DD 256
#define HH 2048
#define DP 64
#define KTOP 16

typedef float f32x4 __attribute__((ext_vector_type(4)));
typedef short short8 __attribute__((ext_vector_type(8)));

__device__ __forceinline__ short f2bf(float x) {
    union { float f; unsigned u; } v; v.f = x;
    unsigned r = v.u + 0x7FFFu + ((v.u >> 16) & 1u);   // round-to-nearest-even
    return (short)(r >> 16);
}
__device__ __forceinline__ float bf2f(short s) {
    union { unsigned u; float f; } v; v.u = ((unsigned)(unsigned short)s) << 16;
    return v.f;
}

// ---------------- Stage 1: Q/K/proj projections + pn normalize (pn -> bf16) ----------------
__global__ __launch_bounds__(64) void proj_kernel(
    const float* __restrict__ act,
    const float* __restrict__ Wq, const float* __restrict__ bq,
    const float* __restrict__ Wk, const float* __restrict__ bk,
    const float* __restrict__ Wc, const float* __restrict__ bc,
    float* __restrict__ Qo, float* __restrict__ Ko, short* __restrict__ Pno)
{
    const int row0 = blockIdx.x * 4;
    const int t = threadIdx.x;
    __shared__ float rowbuf[4][DD];
    const float* src = act + (size_t)row0 * DD;
    for (int i = t; i < 4 * DD; i += 64) rowbuf[i >> 8][i & 255] = src[i];
    __syncthreads();

    float q[4], k[4], c[4];
    #pragma unroll
    for (int r = 0; r < 4; ++r) { q[r] = bq[t]; k[r] = bk[t]; c[r] = bc[t]; }

    for (int d = 0; d < DD; ++d) {
        float wq = Wq[d * DP + t];
        float wk = Wk[d * DP + t];
        float wc = Wc[d * DP + t];
        #pragma unroll
        for (int r = 0; r < 4; ++r) {
            float av = rowbuf[r][d];
            q[r] = fmaf(av, wq, q[r]);
            k[r] = fmaf(av, wk, k[r]);
            c[r] = fmaf(av, wc, c[r]);
        }
    }
    #pragma unroll
    for (int r = 0; r < 4; ++r) {
        float ss = c[r] * c[r];
        #pragma unroll
        for (int off = 32; off; off >>= 1) ss += __shfl_xor(ss, off);
        float nrm = fmaxf(sqrtf(ss), 1e-12f);
        size_t o = (size_t)(row0 + r) * DP + t;
        Qo[o] = q[r];
        Ko[o] = k[r];
        Pno[o] = f2bf(c[r] / nrm);
    }
}

// ---------------- Prep: transpose + bf16 hi/lo split of W2h and Wfh ----------------
__global__ __launch_bounds__(256) void prep_kernel(
    const float* __restrict__ W2h, const float* __restrict__ Wfh,
    short* __restrict__ W2hT_hi, short* __restrict__ W2hT_lo,
    short* __restrict__ WfhT_hi, short* __restrict__ WfhT_lo)
{
    int b = blockIdx.x;
    const float* src; short *dhi, *dlo; int R, C, r0, c0;
    if (b < 512) {               // W2h [256][2048] -> W2hT [2048][256]
        src = W2h; dhi = W2hT_hi; dlo = W2hT_lo; R = 256; C = 2048;
        r0 = (b >> 6) * 32; c0 = (b & 63) * 32;
    } else {                     // Wfh [2048][256] -> WfhT [256][2048]
        b -= 512;
        src = Wfh; dhi = WfhT_hi; dlo = WfhT_lo; R = 2048; C = 256;
        r0 = (b >> 3) * 32; c0 = (b & 7) * 32;
    }
    int tx = threadIdx.x & 31, ty = threadIdx.x >> 5;
    __shared__ float tile[32][33];
    #pragma unroll
    for (int i = 0; i < 4; ++i)
        tile[ty + 8 * i][tx] = src[(size_t)(r0 + ty + 8 * i) * C + c0 + tx];
    __syncthreads();
    #pragma unroll
    for (int i = 0; i < 4; ++i) {
        float v = tile[tx][ty + 8 * i];
        short hi = f2bf(v);
        size_t o = (size_t)(c0 + ty + 8 * i) * R + r0 + tx;
        dhi[o] = hi;
        dlo[o] = f2bf(v - bf2f(hi));
    }
}

// ---------------- Stage 2a: scores + per-wave register top-16 + softmax weights ----------------
// grid: 8192/8 = 1024 blocks, 512 threads (8 waves). Wave w owns row blockIdx.x*8+w.
// K staged through LDS in 128-row chunks (stride 68 to spread banks).
__global__ __launch_bounds__(512, 4) void attn_score_kernel(
    const float* __restrict__ Q, const float* __restrict__ K,
    const float* __restrict__ log_temp,
    float* __restrict__ selw_g, int* __restrict__ seli_g)
{
    const int t = threadIdx.x;
    const int w = t >> 6, l = t & 63;
    const int row = blockIdx.x * 8 + w;
    const int b = row >> 11;

    __shared__ float Ksh[128][68];

    const float temp = fminf(fmaxf(expf(log_temp[0]), 0.1f), 10.0f);
    const float scale = 1.0f / (8.0f * temp);

    const float* Kb = K + (size_t)b * NN * DP;
    const float4* qr4 = (const float4*)(Q + (size_t)row * DP);

    float sc[32];

    for (int ch = 0; ch < 16; ++ch) {
        __syncthreads();
        {   // stage 128 K rows
            int r = t >> 2, seg = t & 3;
            const float4* src = (const float4*)(Kb + (size_t)(ch * 128 + r) * DP + seg * 16);
            float4* dst = (float4*)&Ksh[r][seg * 16];
            dst[0] = src[0]; dst[1] = src[1]; dst[2] = src[2]; dst[3] = src[3];
        }
        __syncthreads();
        float a0 = 0.f, a1 = 0.f;
        const float4* k0 = (const float4*)&Ksh[l][0];
        const float4* k1 = (const float4*)&Ksh[64 + l][0];
        #pragma unroll
        for (int h = 0; h < 2; ++h) {
            float4 q[8];
            #pragma unroll
            for (int i = 0; i < 8; ++i) q[i] = qr4[h * 8 + i];
            #pragma unroll
            for (int i = 0; i < 8; ++i) {
                float4 kv0 = k0[h * 8 + i];
                float4 kv1 = k1[h * 8 + i];
                a0 = fmaf(kv0.x, q[i].x, fmaf(kv0.y, q[i].y, fmaf(kv0.z, q[i].z, fmaf(kv0.w, q[i].w, a0))));
                a1 = fmaf(kv1.x, q[i].x, fmaf(kv1.y, q[i].y, fmaf(kv1.z, q[i].z, fmaf(kv1.w, q[i].w, a1))));
            }
        }
        sc[ch * 2]     = a0 * scale;
        sc[ch * 2 + 1] = a1 * scale;
    }

    // per-wave top-16 tournament; slot i of lane l holds m = (i>>1)*128 + (i&1)*64 + l
    float wv = 0.f; int wm = 0;
    for (int it = 0; it < KTOP; ++it) {
        float bv = sc[0]; int bs = 0;
        #pragma unroll
        for (int i = 1; i < 32; ++i) {
            bool g = sc[i] > bv;            // strict > keeps earliest slot (smallest m)
            bv = g ? sc[i] : bv;
            bs = g ? i : bs;
        }
        int bm = (bs >> 1) * 128 + (bs & 1) * 64 + l;
        #pragma unroll
        for (int off = 1; off < 64; off <<= 1) {
            float ov = __shfl_xor(bv, off);
            int   om = __shfl_xor(bm, off);
            bool take = (ov > bv) || (ov == bv && om < bm);
            bv = take ? ov : bv;
            bm = take ? om : bm;
        }
        if (l == it) { wv = bv; wm = bm; }
        if ((bm & 63) == l) {
            int s = ((bm >> 7) << 1) | ((bm >> 6) & 1);
            #pragma unroll
            for (int i = 0; i < 32; ++i) if (s == i) sc[i] = -3.0e38f;
        }
    }

    // softmax over the 16 winners (lanes 0..15 hold them, descending)
    float mx = __shfl(wv, 0);
    float e = (l < KTOP) ? expf(wv - mx) : 0.f;
    float Z = e;
    #pragma unroll
    for (int off = 1; off < 64; off <<= 1) Z += __shfl_xor(Z, off);
    if (l < KTOP) {
        selw_g[(size_t)row * KTOP + l] = e / Z;
        seli_g[(size_t)row * KTOP + l] = wm;
    }
}

// ---------------- Stage 2b: sparse gather  incoming = sum_k w_k * states[idx_k] ----------------
// grid: 8192/4 = 2048 blocks, 256 threads (4 waves). Wave w owns row blockIdx.x*4+w.
__global__ __launch_bounds__(256) void gather_kernel(
    const float* __restrict__ selw_g, const int* __restrict__ seli_g,
    const float* __restrict__ states, float* __restrict__ incoming)
{
    const int t = threadIdx.x;
    const int w = t >> 6, l = t & 63;
    const int row = blockIdx.x * 4 + w;
    const int b = row >> 11;

    float wv = 0.f; int mi = 0;
    if (l < KTOP) {
        wv = selw_g[(size_t)row * KTOP + l];
        mi = seli_g[(size_t)row * KTOP + l];
    }
    const float* Sb = states + (size_t)b * NN * DD;
    f32x4 acc = (f32x4){0.f, 0.f, 0.f, 0.f};
    #pragma unroll
    for (int kk = 0; kk < KTOP; ++kk) {
        float wk = __shfl(wv, kk);
        int   ik = __shfl(mi, kk);
        const float4 v = *(const float4*)(Sb + (size_t)ik * DD + l * 4);
        acc[0] = fmaf(wk, v.x, acc[0]);
        acc[1] = fmaf(wk, v.y, acc[1]);
        acc[2] = fmaf(wk, v.z, acc[2]);
        acc[3] = fmaf(wk, v.w, acc[3]);
    }
    *(float4*)(incoming + (size_t)row * DD + l * 4) = *(float4*)&acc;
}

// ---------------- Stage 3 (MFMA): sim -> sigmoid -> normalize -> combined -> mixed ----------------
__global__ __launch_bounds__(256) void coal_kernel(
    const short* __restrict__ pnb_g, const float* __restrict__ incoming,
    const float* __restrict__ temp_coal, float* __restrict__ mixed)
{
    const int b  = blockIdx.x >> 7;
    const int rem = blockIdx.x & 127;
    const int n0 = (rem >> 1) * 32;
    const int dh = rem & 1;
    const int t = threadIdx.x;
    const int w = t >> 6;
    const int l = t & 63;

    __shared__ alignas(16) short pnA[32][72];
    __shared__ alignas(16) short pnB[64][72];
    __shared__ alignas(16) short cwt[32][72];
    __shared__ alignas(16) short incT[128][72];
    __shared__ float rowsum[32];

    const size_t bbase = (size_t)b * NN;

    {
        int r = t >> 3, k8 = (t & 7) * 8;
        *(short8*)&pnA[r][k8] = *(const short8*)(pnb_g + (bbase + n0 + r) * DP + k8);
    }
    if (t < 32) rowsum[t] = 0.0f;

    const float tc = temp_coal[0];

    f32x4 acc[2][2];
    #pragma unroll
    for (int i = 0; i < 2; ++i)
        #pragma unroll
        for (int j = 0; j < 2; ++j)
            acc[i][j] = (f32x4){0.f, 0.f, 0.f, 0.f};

    const int lrow = l & 15;
    const int lk   = (l >> 4) * 8;

    for (int ch = 0; ch < 32; ++ch) {
        const int m0 = ch * 64;
        __syncthreads();

        {
            int r = t >> 2, kq = (t & 3) * 16;
            const short* src = pnb_g + (bbase + m0 + r) * DP + kq;
            *(short8*)&pnB[r][kq]     = *(const short8*)src;
            *(short8*)&pnB[r][kq + 8] = *(const short8*)(src + 8);
        }
        {
            int d4 = t & 31;
            int mg = t >> 5;
            const float* incb = incoming + (bbase + m0) * DD + dh * 128 + d4 * 4;
            #pragma unroll
            for (int i = 0; i < 8; ++i) {
                int m = mg * 8 + i;
                float4 v = *(const float4*)(incb + (size_t)m * DD);
                int db = d4 * 4;
                incT[db + 0][m] = f2bf(v.x);
                incT[db + 1][m] = f2bf(v.y);
                incT[db + 2][m] = f2bf(v.z);
                incT[db + 3][m] = f2bf(v.w);
            }
        }
        __syncthreads();

        f32x4 sacc[2];
        sacc[0] = (f32x4){0.f, 0.f, 0.f, 0.f};
        sacc[1] = (f32x4){0.f, 0.f, 0.f, 0.f};
        #pragma unroll
        for (int ks = 0; ks < 2; ++ks) {
            short8 bfr = *(const short8*)&pnB[w * 16 + lrow][lk + ks * 32];
            short8 a0  = *(const short8*)&pnA[lrow][lk + ks * 32];
            short8 a1  = *(const short8*)&pnA[16 + lrow][lk + ks * 32];
            sacc[0] = __builtin_amdgcn_mfma_f32_16x16x32_bf16(a0, bfr, sacc[0], 0, 0, 0);
            sacc[1] = __builtin_amdgcn_mfma_f32_16x16x32_bf16(a1, bfr, sacc[1], 0, 0, 0);
        }
        #pragma unroll
        for (int rt = 0; rt < 2; ++rt) {
            #pragma unroll
            for (int j = 0; j < 4; ++j) {
                int rr = rt * 16 + (l >> 4) * 4 + j;
                int cc = w * 16 + lrow;
                float cv = 1.0f / (1.0f + expf(-(sacc[rt][j] - 0.7f) * tc));
                cwt[rr][cc] = f2bf(cv);
            }
        }
        __syncthreads();

        {
            int r = t >> 3, c8 = (t & 7) * 8;
            short8 cv = *(const short8*)&cwt[r][c8];
            float p = 0.f;
            #pragma unroll
            for (int j = 0; j < 8; ++j) p += bf2f(cv[j]);
            p += __shfl_xor(p, 1);
            p += __shfl_xor(p, 2);
            p += __shfl_xor(p, 4);
            if ((t & 7) == 0) rowsum[r] += p;
        }

        #pragma unroll
        for (int ks = 0; ks < 2; ++ks) {
            short8 a0 = *(const short8*)&cwt[lrow][lk + ks * 32];
            short8 a1 = *(const short8*)&cwt[16 + lrow][lk + ks * 32];
            #pragma unroll
            for (int ct = 0; ct < 2; ++ct) {
                short8 bfr = *(const short8*)&incT[w * 32 + ct * 16 + lrow][lk + ks * 32];
                acc[0][ct] = __builtin_amdgcn_mfma_f32_16x16x32_bf16(a0, bfr, acc[0][ct], 0, 0, 0);
                acc[1][ct] = __builtin_amdgcn_mfma_f32_16x16x32_bf16(a1, bfr, acc[1][ct], 0, 0, 0);
            }
        }
    }
    __syncthreads();

    #pragma unroll
    for (int rt = 0; rt < 2; ++rt) {
        #pragma unroll
        for (int ct = 0; ct < 2; ++ct) {
            #pragma unroll
            for (int j = 0; j < 4; ++j) {
                int rr = rt * 16 + (l >> 4) * 4 + j;
                int cc = w * 32 + ct * 16 + lrow;
                float inv = 1.0f / (rowsum[rr] + 1e-8f);
                float comb = acc[rt][ct][j] * inv;
                size_t gi = (bbase + n0 + rr) * DD + dh * 128 + cc;
                mixed[gi] = 0.8f * incoming[gi] + 0.2f * comb;
            }
        }
    }
}

// ---------------- Stage 4a (MFMA): z = mixed@W2h + b2h -> q bits, strength ----------------
#define PADA 264
#define PADW 136
__global__ __launch_bounds__(256) void hdcA_kernel(
    const float* __restrict__ mixed, const float* __restrict__ mem,
    const short* __restrict__ W2hT_hi, const short* __restrict__ W2hT_lo,
    const float* __restrict__ b2h,
    const float* __restrict__ keys, const float* __restrict__ pos_codes,
    const int* __restrict__ step,
    unsigned short* __restrict__ qbits, float* __restrict__ strength)
{
    const int row0 = blockIdx.x * 32;
    const int t = threadIdx.x;
    const int w = t >> 6, l = t & 63;
    const int lr = l & 15, lg = l >> 4;

    __shared__ short Ahi[32][PADA], Alo[32][PADA];
    __shared__ short Whi[64][PADW], Wlo[64][PADW];
    __shared__ float redN[32][4], redS[32][4];

    for (int idx = t; idx < 32 * 256; idx += 256) {
        int r = idx >> 8, c = idx & 255;
        float v = mixed[(size_t)(row0 + r) * DD + c];
        short hi = f2bf(v);
        Ahi[r][c] = hi;
        Alo[r][c] = f2bf(v - bf2f(hi));
    }

    int st = ((step[0] % 256) + 256) % 256;
    const float* pos = pos_codes + (size_t)st * HH;

    float num8[8], ns8[8];
    #pragma unroll
    for (int i = 0; i < 8; ++i) { num8[i] = 0.f; ns8[i] = 0.f; }

    for (int ch = 0; ch < 32; ++ch) {
        const int h0 = ch * 64;
        f32x4 zac[2];
        zac[0] = (f32x4){0.f, 0.f, 0.f, 0.f};
        zac[1] = (f32x4){0.f, 0.f, 0.f, 0.f};
        for (int ks = 0; ks < 2; ++ks) {
            const int k0 = ks * 128;
            __syncthreads();
            {
                int r = t >> 2, cb = (t & 3) * 32;
                const short* sh = W2hT_hi + (size_t)(h0 + r) * DD + k0 + cb;
                const short* sl = W2hT_lo + (size_t)(h0 + r) * DD + k0 + cb;
                #pragma unroll
                for (int j = 0; j < 4; ++j) {
                    *(short8*)&Whi[r][cb + j * 8] = *(const short8*)(sh + j * 8);
                    *(short8*)&Wlo[r][cb + j * 8] = *(const short8*)(sl + j * 8);
                }
            }
            __syncthreads();
            #pragma unroll
            for (int kt = 0; kt < 4; ++kt) {
                int kk = k0 + kt * 32 + lg * 8;
                int kw = kt * 32 + lg * 8;
                short8 bhi = *(const short8*)&Whi[w * 16 + lr][kw];
                short8 blo = *(const short8*)&Wlo[w * 16 + lr][kw];
                #pragma unroll
                for (int mt = 0; mt < 2; ++mt) {
                    short8 ahi = *(const short8*)&Ahi[mt * 16 + lr][kk];
                    short8 alo = *(const short8*)&Alo[mt * 16 + lr][kk];
                    zac[mt] = __builtin_amdgcn_mfma_f32_16x16x32_bf16(ahi, bhi, zac[mt], 0, 0, 0);
                    zac[mt] = __builtin_amdgcn_mfma_f32_16x16x32_bf16(ahi, blo, zac[mt], 0, 0, 0);
                    zac[mt] = __builtin_amdgcn_mfma_f32_16x16x32_bf16(alo, bhi, zac[mt], 0, 0, 0);
                }
            }
        }
        const int h = h0 + w * 16 + lr;
        const float bv = b2h[h], pv = pos[h];
        #pragma unroll
        for (int mt = 0; mt < 2; ++mt) {
            #pragma unroll
            for (int j = 0; j < 4; ++j) {
                int row = row0 + mt * 16 + lg * 4 + j;
                float z = zac[mt][j] + bv;
                float q = (z >= 0.f) ? 1.f : -1.f;
                unsigned long long bal = __ballot(z >= 0.f);
                if (lr == 0)
                    qbits[(size_t)row * 128 + (h0 >> 4) + w] =
                        (unsigned short)((bal >> (lg * 16)) & 0xFFFFull);
                float nmv = 0.95f * mem[(size_t)row * HH + h] + 0.05f * q * pv;
                float pq = q * keys[(size_t)(row & (NN - 1)) * HH + h];
                num8[mt * 4 + j] = fmaf(nmv, pq, num8[mt * 4 + j]);
                ns8[mt * 4 + j]  = fmaf(nmv, nmv, ns8[mt * 4 + j]);
            }
        }
    }

    #pragma unroll
    for (int i = 0; i < 8; ++i) {
        #pragma unroll
        for (int off = 1; off < 16; off <<= 1) {
            num8[i] += __shfl_xor(num8[i], off);
            ns8[i]  += __shfl_xor(ns8[i], off);
        }
    }
    if (lr == 0) {
        #pragma unroll
        for (int mt = 0; mt < 2; ++mt)
            #pragma unroll
            for (int j = 0; j < 4; ++j) {
                redN[mt * 16 + lg * 4 + j][w] = num8[mt * 4 + j];
                redS[mt * 16 + lg * 4 + j][w] = ns8[mt * 4 + j];
            }
    }
    __syncthreads();
    if (t < 32) {
        float num = redN[t][0] + redN[t][1] + redN[t][2] + redN[t][3];
        float ns  = redS[t][0] + redS[t][1] + redS[t][2] + redS[t][3];
        float cosv = num / (fmaxf(sqrtf(ns), 1e-8f) * sqrtf(2048.0f));
        strength[row0 + t] = 1.0f / (1.0f + expf(-cosv));
    }
}

// ---------------- Stage 4b (MFMA): recall = nm@Wfh; out = mixed + (recall+bfh)*strength ----------------
__global__ __launch_bounds__(256) void hdcB_kernel(
    const float* __restrict__ mem, const unsigned short* __restrict__ qbits,
    const float* __restrict__ pos_codes, const int* __restrict__ step,
    const short* __restrict__ WfhT_hi, const short* __restrict__ WfhT_lo,
    const float* __restrict__ bfh, const float* __restrict__ strength,
    const float* __restrict__ mixed, float* __restrict__ out)
{
    const int mb = blockIdx.x >> 1, nb = blockIdx.x & 1;
    const int row0 = mb * 64, d0 = nb * 128;
    const int t = threadIdx.x;
    const int w = t >> 6, l = t & 63;
    const int wm = w >> 1, wn = w & 1;
    const int lr = l & 15, lg = l >> 4;

    __shared__ short Ahi[64][72], Alo[64][72];
    __shared__ short Bhi[128][72], Blo[128][72];

    int st = ((step[0] % 256) + 256) % 256;
    const float* pos = pos_codes + (size_t)st * HH;

    f32x4 acc[2][4];
    #pragma unroll
    for (int i = 0; i < 2; ++i)
        #pragma unroll
        for (int j = 0; j < 4; ++j)
            acc[i][j] = (f32x4){0.f, 0.f, 0.f, 0.f};

    for (int kc = 0; kc < 32; ++kc) {
        const int h0 = kc * 64;
        __syncthreads();
        {
            int r = t >> 2, hb = (t & 3) * 16;
            const float* src = mem + (size_t)(row0 + r) * HH + h0 + hb;
            unsigned bits = qbits[(size_t)(row0 + r) * 128 + ((h0 + hb) >> 4)];
            #pragma unroll
            for (int j4 = 0; j4 < 4; ++j4) {
                float4 mv = *(const float4*)(src + j4 * 4);
                #pragma unroll
                for (int j = 0; j < 4; ++j) {
                    int jj = j4 * 4 + j;
                    float memv = (j == 0) ? mv.x : (j == 1) ? mv.y : (j == 2) ? mv.z : mv.w;
                    float q = (bits >> jj) & 1u ? 1.f : -1.f;
                    float nmv = 0.95f * memv + 0.05f * q * pos[h0 + hb + jj];
                    short hi = f2bf(nmv);
                    Ahi[r][hb + jj] = hi;
                    Alo[r][hb + jj] = f2bf(nmv - bf2f(hi));
                }
            }
        }
        {
            int r = t >> 1, hb = (t & 1) * 32;
            const short* sh = WfhT_hi + (size_t)(d0 + r) * HH + h0 + hb;
            const short* sl = WfhT_lo + (size_t)(d0 + r) * HH + h0 + hb;
            #pragma unroll
            for (int j = 0; j < 4; ++j) {
                *(short8*)&Bhi[r][hb + j * 8] = *(const short8*)(sh + j * 8);
                *(short8*)&Blo[r][hb + j * 8] = *(const short8*)(sl + j * 8);
            }
        }
        __syncthreads();
        #pragma unroll
        for (int kt = 0; kt < 2; ++kt) {
            int kk = kt * 32 + lg * 8;
            #pragma unroll
            for (int mt = 0; mt < 2; ++mt) {
                short8 ahi = *(const short8*)&Ahi[wm * 32 + mt * 16 + lr][kk];
                short8 alo = *(const short8*)&Alo[wm * 32 + mt * 16 + lr][kk];
                #pragma unroll
                for (int nt = 0; nt < 4; ++nt) {
                    short8 bhi = *(const short8*)&Bhi[wn * 64 + nt * 16 + lr][kk];
                    short8 blo = *(const short8*)&Blo[wn * 64 + nt * 16 + lr][kk];
                    acc[mt][nt] = __builtin_amdgcn_mfma_f32_16x16x32_bf16(ahi, bhi, acc[mt][nt], 0, 0, 0);
                    acc[mt][nt] = __builtin_amdgcn_mfma_f32_16x16x32_bf16(ahi, blo, acc[mt][nt], 0, 0, 0);
                    acc[mt][nt] = __builtin_amdgcn_mfma_f32_16x16x32_bf16(alo, bhi, acc[mt][nt], 0, 0, 0);
                }
            }
        }
    }

    #pragma unroll
    for (int mt = 0; mt < 2; ++mt) {
        #pragma unroll
        for (int nt = 0; nt < 4; ++nt) {
            #pragma unroll
            for (int j = 0; j < 4; ++j) {
                int row = row0 + wm * 32 + mt * 16 + lg * 4 + j;
                int col = d0 + wn * 64 + nt * 16 + lr;
                float sv = strength[row];
                size_t gi = (size_t)row * DD + col;
                out[gi] = mixed[gi] + (acc[mt][nt][j] + bfh[col]) * sv;
            }
        }
    }
}

extern "C" void kernel_launch(void* const* d_in, const int* in_sizes, int n_in,
                              void* d_out, int out_size, void* d_ws, size_t ws_size,
                              hipStream_t stream) {
    const float* states    = (const float*)d_in[0];
    const float* actions   = (const float*)d_in[1];
    const float* mem       = (const float*)d_in[2];
    const float* Wq        = (const float*)d_in[3];
    const float* bq        = (const float*)d_in[4];
    const float* Wk        = (const float*)d_in[5];
    const float* bk        = (const float*)d_in[6];
    const float* log_temp  = (const float*)d_in[7];
    const float* Wc        = (const float*)d_in[8];
    const float* bc        = (const float*)d_in[9];
    const float* temp_coal = (const float*)d_in[10];
    const float* W2h       = (const float*)d_in[11];
    const float* b2h       = (const float*)d_in[12];
    const float* Wfh       = (const float*)d_in[13];
    const float* bfh       = (const float*)d_in[14];
    const float* keys      = (const float*)d_in[15];
    const float* pos_codes = (const float*)d_in[16];
    const int*   step      = (const int*)d_in[17];
    float* out = (float*)d_out;

    float* ws = (float*)d_ws;
    float* mixed    = ws;                                    // 2,097,152 f32
    short* W2hT_hi  = (short*)(mixed + 2097152);             // 524288 shorts
    short* W2hT_lo  = W2hT_hi + 524288;
    short* WfhT_hi  = W2hT_lo + 524288;
    short* WfhT_lo  = WfhT_hi + 524288;
    float* strength = (float*)(WfhT_lo + 524288);            // 8192 f32
    unsigned short* qbits = (unsigned short*)(strength + 8192);  // 1,048,576 u16
    float* Q        = (float*)(qbits + 1048576);             // 524288 f32
    float* K        = Q + 524288;
    float* incoming = K + 524288;                            // 2,097,152 f32
    short* pn_bf    = (short*)(incoming + 2097152);          // 524288 shorts
    float* selw     = (float*)(pn_bf + 524288);              // 131072 f32
    int*   seli     = (int*)(selw + 131072);                 // 131072 i32

    proj_kernel<<<BATCH * NN / 4, 64, 0, stream>>>(actions, Wq, bq, Wk, bk, Wc, bc, Q, K, pn_bf);
    prep_kernel<<<1024, 256, 0, stream>>>(W2h, Wfh, W2hT_hi, W2hT_lo, WfhT_hi, WfhT_lo);
    attn_score_kernel<<<BATCH * NN / 8, 512, 0, stream>>>(Q, K, log_temp, selw, seli);
    gather_kernel<<<BATCH * NN / 4, 256, 0, stream>>>(selw, seli, states, incoming);
    coal_kernel<<<BATCH * (NN / 32) * 2, 256, 0, stream>>>(pn_bf, incoming, temp_coal, mixed);
    hdcA_kernel<<<BATCH * NN / 32, 256, 0, stream>>>(mixed, mem, W2hT_hi, W2hT_lo, b2h,
                                                     keys, pos_codes, step, qbits, strength);
    hdcB_kernel<<<(BATCH * NN / 64) * 2, 256, 0, stream>>>(mem, qbits, pos_codes, step,
                                                           WfhT_hi, WfhT_lo, bfh, strength,
                                                           mixed, out);
}

// Round 5
// 364.286 us; speedup vs baseline: 6.0847x; 1.1807x over previous
//
#include <hip/hip_runtime.h>
#include <math.h>

#define BATCH 4
#define NN 2048
#define DD 256
#define HH 2048
#define DP 64
#define KTOP 16

typedef float f32x4 __attribute__((ext_vector_type(4)));
typedef short short8 __attribute__((ext_vector_type(8)));
typedef short short4v __attribute__((ext_vector_type(4)));

__device__ __forceinline__ short f2bf(float x) {
    union { float f; unsigned u; } v; v.f = x;
    unsigned r = v.u + 0x7FFFu + ((v.u >> 16) & 1u);   // round-to-nearest-even
    return (short)(r >> 16);
}
__device__ __forceinline__ float bf2f(short s) {
    union { unsigned u; float f; } v; v.u = ((unsigned)(unsigned short)s) << 16;
    return v.f;
}

// ---------------- Stage 1: Q/K/proj projections + pn normalize (pn -> bf16) ----------------
__global__ __launch_bounds__(64) void proj_kernel(
    const float* __restrict__ act,
    const float* __restrict__ Wq, const float* __restrict__ bq,
    const float* __restrict__ Wk, const float* __restrict__ bk,
    const float* __restrict__ Wc, const float* __restrict__ bc,
    float* __restrict__ Qo, float* __restrict__ Ko, short* __restrict__ Pno)
{
    const int row0 = blockIdx.x * 4;
    const int t = threadIdx.x;
    __shared__ float rowbuf[4][DD];
    const float* src = act + (size_t)row0 * DD;
    for (int i = t; i < 4 * DD; i += 64) rowbuf[i >> 8][i & 255] = src[i];
    __syncthreads();

    float q[4], k[4], c[4];
    #pragma unroll
    for (int r = 0; r < 4; ++r) { q[r] = bq[t]; k[r] = bk[t]; c[r] = bc[t]; }

    for (int d = 0; d < DD; ++d) {
        float wq = Wq[d * DP + t];
        float wk = Wk[d * DP + t];
        float wc = Wc[d * DP + t];
        #pragma unroll
        for (int r = 0; r < 4; ++r) {
            float av = rowbuf[r][d];
            q[r] = fmaf(av, wq, q[r]);
            k[r] = fmaf(av, wk, k[r]);
            c[r] = fmaf(av, wc, c[r]);
        }
    }
    #pragma unroll
    for (int r = 0; r < 4; ++r) {
        float ss = c[r] * c[r];
        #pragma unroll
        for (int off = 32; off; off >>= 1) ss += __shfl_xor(ss, off);
        float nrm = fmaxf(sqrtf(ss), 1e-12f);
        size_t o = (size_t)(row0 + r) * DP + t;
        Qo[o] = q[r];
        Ko[o] = k[r];
        Pno[o] = f2bf(c[r] / nrm);
    }
}

// ---------------- Prep: transpose + bf16 hi/lo split of W2h and Wfh ----------------
__global__ __launch_bounds__(256) void prep_kernel(
    const float* __restrict__ W2h, const float* __restrict__ Wfh,
    short* __restrict__ W2hT_hi, short* __restrict__ W2hT_lo,
    short* __restrict__ WfhT_hi, short* __restrict__ WfhT_lo)
{
    int b = blockIdx.x;
    const float* src; short *dhi, *dlo; int R, C, r0, c0;
    if (b < 512) {               // W2h [256][2048] -> W2hT [2048][256]
        src = W2h; dhi = W2hT_hi; dlo = W2hT_lo; R = 256; C = 2048;
        r0 = (b >> 6) * 32; c0 = (b & 63) * 32;
    } else {                     // Wfh [2048][256] -> WfhT [256][2048]
        b -= 512;
        src = Wfh; dhi = WfhT_hi; dlo = WfhT_lo; R = 2048; C = 256;
        r0 = (b >> 3) * 32; c0 = (b & 7) * 32;
    }
    int tx = threadIdx.x & 31, ty = threadIdx.x >> 5;
    __shared__ float tile[32][33];
    #pragma unroll
    for (int i = 0; i < 4; ++i)
        tile[ty + 8 * i][tx] = src[(size_t)(r0 + ty + 8 * i) * C + c0 + tx];
    __syncthreads();
    #pragma unroll
    for (int i = 0; i < 4; ++i) {
        float v = tile[tx][ty + 8 * i];
        short hi = f2bf(v);
        size_t o = (size_t)(c0 + ty + 8 * i) * R + r0 + tx;
        dhi[o] = hi;
        dlo[o] = f2bf(v - bf2f(hi));
    }
}

// ---------------- Stage 2a: scores + per-wave register top-16 + softmax weights ----------------
__global__ __launch_bounds__(512, 4) void attn_score_kernel(
    const float* __restrict__ Q, const float* __restrict__ K,
    const float* __restrict__ log_temp,
    float* __restrict__ selw_g, int* __restrict__ seli_g)
{
    const int t = threadIdx.x;
    const int w = t >> 6, l = t & 63;
    const int row = blockIdx.x * 8 + w;
    const int b = row >> 11;

    __shared__ float Ksh[128][68];

    const float temp = fminf(fmaxf(expf(log_temp[0]), 0.1f), 10.0f);
    const float scale = 1.0f / (8.0f * temp);

    const float* Kb = K + (size_t)b * NN * DP;
    const float4* qr4 = (const float4*)(Q + (size_t)row * DP);

    float sc[32];

    for (int ch = 0; ch < 16; ++ch) {
        __syncthreads();
        {   // stage 128 K rows
            int r = t >> 2, seg = t & 3;
            const float4* src = (const float4*)(Kb + (size_t)(ch * 128 + r) * DP + seg * 16);
            float4* dst = (float4*)&Ksh[r][seg * 16];
            dst[0] = src[0]; dst[1] = src[1]; dst[2] = src[2]; dst[3] = src[3];
        }
        __syncthreads();
        float a0 = 0.f, a1 = 0.f;
        const float4* k0 = (const float4*)&Ksh[l][0];
        const float4* k1 = (const float4*)&Ksh[64 + l][0];
        #pragma unroll
        for (int h = 0; h < 2; ++h) {
            float4 q[8];
            #pragma unroll
            for (int i = 0; i < 8; ++i) q[i] = qr4[h * 8 + i];
            #pragma unroll
            for (int i = 0; i < 8; ++i) {
                float4 kv0 = k0[h * 8 + i];
                float4 kv1 = k1[h * 8 + i];
                a0 = fmaf(kv0.x, q[i].x, fmaf(kv0.y, q[i].y, fmaf(kv0.z, q[i].z, fmaf(kv0.w, q[i].w, a0))));
                a1 = fmaf(kv1.x, q[i].x, fmaf(kv1.y, q[i].y, fmaf(kv1.z, q[i].z, fmaf(kv1.w, q[i].w, a1))));
            }
        }
        sc[ch * 2]     = a0 * scale;
        sc[ch * 2 + 1] = a1 * scale;
    }

    // per-wave top-16 tournament; slot i of lane l holds m = (i>>1)*128 + (i&1)*64 + l
    float wv = 0.f; int wm = 0;
    for (int it = 0; it < KTOP; ++it) {
        float bv = sc[0]; int bs = 0;
        #pragma unroll
        for (int i = 1; i < 32; ++i) {
            bool g = sc[i] > bv;
            bv = g ? sc[i] : bv;
            bs = g ? i : bs;
        }
        int bm = (bs >> 1) * 128 + (bs & 1) * 64 + l;
        #pragma unroll
        for (int off = 1; off < 64; off <<= 1) {
            float ov = __shfl_xor(bv, off);
            int   om = __shfl_xor(bm, off);
            bool take = (ov > bv) || (ov == bv && om < bm);
            bv = take ? ov : bv;
            bm = take ? om : bm;
        }
        if (l == it) { wv = bv; wm = bm; }
        if ((bm & 63) == l) {
            int s = ((bm >> 7) << 1) | ((bm >> 6) & 1);
            #pragma unroll
            for (int i = 0; i < 32; ++i) if (s == i) sc[i] = -3.0e38f;
        }
    }

    float mx = __shfl(wv, 0);
    float e = (l < KTOP) ? expf(wv - mx) : 0.f;
    float Z = e;
    #pragma unroll
    for (int off = 1; off < 64; off <<= 1) Z += __shfl_xor(Z, off);
    if (l < KTOP) {
        selw_g[(size_t)row * KTOP + l] = e / Z;
        seli_g[(size_t)row * KTOP + l] = wm;
    }
}

// ---------------- Stage 2b: sparse gather ----------------
__global__ __launch_bounds__(256) void gather_kernel(
    const float* __restrict__ selw_g, const int* __restrict__ seli_g,
    const float* __restrict__ states, float* __restrict__ incoming)
{
    const int t = threadIdx.x;
    const int w = t >> 6, l = t & 63;
    const int row = blockIdx.x * 4 + w;
    const int b = row >> 11;

    float wv = 0.f; int mi = 0;
    if (l < KTOP) {
        wv = selw_g[(size_t)row * KTOP + l];
        mi = seli_g[(size_t)row * KTOP + l];
    }
    const float* Sb = states + (size_t)b * NN * DD;
    f32x4 acc = (f32x4){0.f, 0.f, 0.f, 0.f};
    #pragma unroll
    for (int kk = 0; kk < KTOP; ++kk) {
        float wk = __shfl(wv, kk);
        int   ik = __shfl(mi, kk);
        const float4 v = *(const float4*)(Sb + (size_t)ik * DD + l * 4);
        acc[0] = fmaf(wk, v.x, acc[0]);
        acc[1] = fmaf(wk, v.y, acc[1]);
        acc[2] = fmaf(wk, v.z, acc[2]);
        acc[3] = fmaf(wk, v.w, acc[3]);
    }
    *(float4*)(incoming + (size_t)row * DD + l * 4) = *(float4*)&acc;
}

// ---------------- Stage 3 (MFMA): sim -> sigmoid -> normalize -> combined -> mixed ----------------
__global__ __launch_bounds__(256) void coal_kernel(
    const short* __restrict__ pnb_g, const float* __restrict__ incoming,
    const float* __restrict__ temp_coal, float* __restrict__ mixed)
{
    const int b  = blockIdx.x >> 7;
    const int rem = blockIdx.x & 127;
    const int n0 = (rem >> 1) * 32;
    const int dh = rem & 1;
    const int t = threadIdx.x;
    const int w = t >> 6;
    const int l = t & 63;

    __shared__ alignas(16) short pnA[32][72];
    __shared__ alignas(16) short pnB[64][72];
    __shared__ alignas(16) short cwt[32][72];
    __shared__ alignas(16) short incT[128][72];
    __shared__ float rowsum[32];

    const size_t bbase = (size_t)b * NN;

    {
        int r = t >> 3, k8 = (t & 7) * 8;
        *(short8*)&pnA[r][k8] = *(const short8*)(pnb_g + (bbase + n0 + r) * DP + k8);
    }
    if (t < 32) rowsum[t] = 0.0f;

    const float tc = temp_coal[0];

    f32x4 acc[2][2];
    #pragma unroll
    for (int i = 0; i < 2; ++i)
        #pragma unroll
        for (int j = 0; j < 2; ++j)
            acc[i][j] = (f32x4){0.f, 0.f, 0.f, 0.f};

    const int lrow = l & 15;
    const int lk   = (l >> 4) * 8;

    for (int ch = 0; ch < 32; ++ch) {
        const int m0 = ch * 64;
        __syncthreads();

        {
            int r = t >> 2, kq = (t & 3) * 16;
            const short* src = pnb_g + (bbase + m0 + r) * DP + kq;
            *(short8*)&pnB[r][kq]     = *(const short8*)src;
            *(short8*)&pnB[r][kq + 8] = *(const short8*)(src + 8);
        }
        {
            int d4 = t & 31;
            int mg = t >> 5;
            const float* incb = incoming + (bbase + m0) * DD + dh * 128 + d4 * 4;
            #pragma unroll
            for (int i = 0; i < 8; ++i) {
                int m = mg * 8 + i;
                float4 v = *(const float4*)(incb + (size_t)m * DD);
                int db = d4 * 4;
                incT[db + 0][m] = f2bf(v.x);
                incT[db + 1][m] = f2bf(v.y);
                incT[db + 2][m] = f2bf(v.z);
                incT[db + 3][m] = f2bf(v.w);
            }
        }
        __syncthreads();

        f32x4 sacc[2];
        sacc[0] = (f32x4){0.f, 0.f, 0.f, 0.f};
        sacc[1] = (f32x4){0.f, 0.f, 0.f, 0.f};
        #pragma unroll
        for (int ks = 0; ks < 2; ++ks) {
            short8 bfr = *(const short8*)&pnB[w * 16 + lrow][lk + ks * 32];
            short8 a0  = *(const short8*)&pnA[lrow][lk + ks * 32];
            short8 a1  = *(const short8*)&pnA[16 + lrow][lk + ks * 32];
            sacc[0] = __builtin_amdgcn_mfma_f32_16x16x32_bf16(a0, bfr, sacc[0], 0, 0, 0);
            sacc[1] = __builtin_amdgcn_mfma_f32_16x16x32_bf16(a1, bfr, sacc[1], 0, 0, 0);
        }
        #pragma unroll
        for (int rt = 0; rt < 2; ++rt) {
            #pragma unroll
            for (int j = 0; j < 4; ++j) {
                int rr = rt * 16 + (l >> 4) * 4 + j;
                int cc = w * 16 + lrow;
                float cv = 1.0f / (1.0f + expf(-(sacc[rt][j] - 0.7f) * tc));
                cwt[rr][cc] = f2bf(cv);
            }
        }
        __syncthreads();

        {
            int r = t >> 3, c8 = (t & 7) * 8;
            short8 cv = *(const short8*)&cwt[r][c8];
            float p = 0.f;
            #pragma unroll
            for (int j = 0; j < 8; ++j) p += bf2f(cv[j]);
            p += __shfl_xor(p, 1);
            p += __shfl_xor(p, 2);
            p += __shfl_xor(p, 4);
            if ((t & 7) == 0) rowsum[r] += p;
        }

        #pragma unroll
        for (int ks = 0; ks < 2; ++ks) {
            short8 a0 = *(const short8*)&cwt[lrow][lk + ks * 32];
            short8 a1 = *(const short8*)&cwt[16 + lrow][lk + ks * 32];
            #pragma unroll
            for (int ct = 0; ct < 2; ++ct) {
                short8 bfr = *(const short8*)&incT[w * 32 + ct * 16 + lrow][lk + ks * 32];
                acc[0][ct] = __builtin_amdgcn_mfma_f32_16x16x32_bf16(a0, bfr, acc[0][ct], 0, 0, 0);
                acc[1][ct] = __builtin_amdgcn_mfma_f32_16x16x32_bf16(a1, bfr, acc[1][ct], 0, 0, 0);
            }
        }
    }
    __syncthreads();

    #pragma unroll
    for (int rt = 0; rt < 2; ++rt) {
        #pragma unroll
        for (int ct = 0; ct < 2; ++ct) {
            #pragma unroll
            for (int j = 0; j < 4; ++j) {
                int rr = rt * 16 + (l >> 4) * 4 + j;
                int cc = w * 32 + ct * 16 + lrow;
                float inv = 1.0f / (rowsum[rr] + 1e-8f);
                float comb = acc[rt][ct][j] * inv;
                size_t gi = (bbase + n0 + rr) * DD + dh * 128 + cc;
                mixed[gi] = 0.8f * incoming[gi] + 0.2f * comb;
            }
        }
    }
}

// ---------------- Stage 4a (MFMA): z = mixed@W2h + b2h -> q bits only ----------------
// grid: 256 row-blocks x 8 h-segments = 2048 blocks, 256 threads (4 waves).
// Block: 32 rows x 256-h segment; 3-term bf16 split (~fp32-exact signs).
__global__ __launch_bounds__(256) void hdcA_kernel(
    const float* __restrict__ mixed,
    const short* __restrict__ W2hT_hi, const short* __restrict__ W2hT_lo,
    const float* __restrict__ b2h,
    unsigned short* __restrict__ qbits)
{
    const int rb = blockIdx.x >> 3;
    const int hs = blockIdx.x & 7;
    const int row0 = rb * 32;
    const int hbase = hs * 256;
    const int t = threadIdx.x;
    const int w = t >> 6, l = t & 63;
    const int lr = l & 15, lg = l >> 4;

    __shared__ short Ahi[32][264], Alo[32][264];
    __shared__ short Whi[64][136], Wlo[64][136];

    #pragma unroll
    for (int i = 0; i < 8; ++i) {       // stage A: 32 rows x 256 k (vectorized)
        int idx = t + i * 256;
        int r = idx >> 6, c = (idx & 63) * 4;
        float4 v = *(const float4*)(mixed + (size_t)(row0 + r) * DD + c);
        short4v hi4, lo4;
        hi4[0] = f2bf(v.x); lo4[0] = f2bf(v.x - bf2f(hi4[0]));
        hi4[1] = f2bf(v.y); lo4[1] = f2bf(v.y - bf2f(hi4[1]));
        hi4[2] = f2bf(v.z); lo4[2] = f2bf(v.z - bf2f(hi4[2]));
        hi4[3] = f2bf(v.w); lo4[3] = f2bf(v.w - bf2f(hi4[3]));
        *(short4v*)&Ahi[r][c] = hi4;
        *(short4v*)&Alo[r][c] = lo4;
    }

    for (int ch = 0; ch < 4; ++ch) {
        const int h0 = hbase + ch * 64;
        f32x4 zac[2];
        zac[0] = (f32x4){0.f, 0.f, 0.f, 0.f};
        zac[1] = (f32x4){0.f, 0.f, 0.f, 0.f};
        #pragma unroll
        for (int ks = 0; ks < 2; ++ks) {
            const int k0 = ks * 128;
            __syncthreads();
            {
                int r = t >> 2, cb = (t & 3) * 32;
                const short* sh = W2hT_hi + (size_t)(h0 + r) * DD + k0 + cb;
                const short* sl = W2hT_lo + (size_t)(h0 + r) * DD + k0 + cb;
                #pragma unroll
                for (int j = 0; j < 4; ++j) {
                    *(short8*)&Whi[r][cb + j * 8] = *(const short8*)(sh + j * 8);
                    *(short8*)&Wlo[r][cb + j * 8] = *(const short8*)(sl + j * 8);
                }
            }
            __syncthreads();
            #pragma unroll
            for (int kt = 0; kt < 4; ++kt) {
                int kk = k0 + kt * 32 + lg * 8;
                int kw = kt * 32 + lg * 8;
                short8 bhi = *(const short8*)&Whi[w * 16 + lr][kw];
                short8 blo = *(const short8*)&Wlo[w * 16 + lr][kw];
                #pragma unroll
                for (int mt = 0; mt < 2; ++mt) {
                    short8 ahi = *(const short8*)&Ahi[mt * 16 + lr][kk];
                    short8 alo = *(const short8*)&Alo[mt * 16 + lr][kk];
                    zac[mt] = __builtin_amdgcn_mfma_f32_16x16x32_bf16(ahi, bhi, zac[mt], 0, 0, 0);
                    zac[mt] = __builtin_amdgcn_mfma_f32_16x16x32_bf16(ahi, blo, zac[mt], 0, 0, 0);
                    zac[mt] = __builtin_amdgcn_mfma_f32_16x16x32_bf16(alo, bhi, zac[mt], 0, 0, 0);
                }
            }
        }
        const float bv = b2h[h0 + w * 16 + lr];
        #pragma unroll
        for (int mt = 0; mt < 2; ++mt) {
            #pragma unroll
            for (int j = 0; j < 4; ++j) {
                float z = zac[mt][j] + bv;
                unsigned long long bal = __ballot(z >= 0.0f);
                if (lr == 0)
                    qbits[(size_t)(row0 + mt * 16 + lg * 4 + j) * 128 + (h0 >> 4) + w] =
                        (unsigned short)((bal >> (lg * 16)) & 0xFFFFull);
            }
        }
    }
}

// ---------------- Stage 4b (MFMA): nm recompute + num/ns + strength + recall + out ----------------
// grid: 128 row-blocks x 2 d-halves = 256 blocks, 512 threads (8 waves: 4m x 2n).
// 2-term split (A exact, B bf16-hi) — recall error ~2e-3 << threshold.
__global__ __launch_bounds__(512) void hdcB_kernel(
    const float* __restrict__ mem, const unsigned short* __restrict__ qbits,
    const float* __restrict__ pos_codes, const int* __restrict__ step,
    const short* __restrict__ WfhT_hi,
    const float* __restrict__ bfh, const float* __restrict__ keys,
    const float* __restrict__ mixed, float* __restrict__ out)
{
    const int mb = blockIdx.x >> 1, nb = blockIdx.x & 1;
    const int row0 = mb * 64, d0 = nb * 128;
    const int t = threadIdx.x;
    const int w = t >> 6, l = t & 63;
    const int wm = w >> 1, wn = w & 1;
    const int lr = l & 15, lg = l >> 4;

    __shared__ short Ahi[64][72], Alo[64][72];
    __shared__ short Bhi[128][72];
    __shared__ float sred[64][2];
    __shared__ float strenL[64];

    int st = ((step[0] % 256) + 256) % 256;
    const float* pos = pos_codes + (size_t)st * HH;

    f32x4 acc[4];
    #pragma unroll
    for (int i = 0; i < 4; ++i) acc[i] = (f32x4){0.f, 0.f, 0.f, 0.f};
    float pnum = 0.f, pns = 0.f;

    const int ar = t >> 3;              // row 0..63
    const int ah = (t & 7) * 8;         // h offset within chunk
    const int arow = row0 + ar;
    const size_t memb = (size_t)arow * HH;
    const size_t keyb = (size_t)(arow & (NN - 1)) * HH;

    for (int kc = 0; kc < 32; ++kc) {
        const int h0 = kc * 64;
        __syncthreads();
        {   // A stage: nm recompute + num/ns partials (coalesced float4 loads)
            float mv[8], kv[8], pv[8];
            *(float4*)&mv[0] = *(const float4*)(mem + memb + h0 + ah);
            *(float4*)&mv[4] = *(const float4*)(mem + memb + h0 + ah + 4);
            *(float4*)&kv[0] = *(const float4*)(keys + keyb + h0 + ah);
            *(float4*)&kv[4] = *(const float4*)(keys + keyb + h0 + ah + 4);
            *(float4*)&pv[0] = *(const float4*)(pos + h0 + ah);
            *(float4*)&pv[4] = *(const float4*)(pos + h0 + ah + 4);
            unsigned bits = (unsigned)qbits[(size_t)arow * 128 + ((h0 + ah) >> 4)] >> (ah & 8);
            short hi8[8], lo8[8];
            #pragma unroll
            for (int j = 0; j < 8; ++j) {
                float q = ((bits >> j) & 1u) ? 1.0f : -1.0f;
                float nmv = fmaf(0.05f * q, pv[j], 0.95f * mv[j]);
                pnum = fmaf(nmv, q * kv[j], pnum);
                pns  = fmaf(nmv, nmv, pns);
                hi8[j] = f2bf(nmv);
                lo8[j] = f2bf(nmv - bf2f(hi8[j]));
            }
            *(short8*)&Ahi[ar][ah] = *(short8*)hi8;
            *(short8*)&Alo[ar][ah] = *(short8*)lo8;
        }
        {   // B stage: WfhT 128 x 64 (hi only)
            int r = t >> 2, hb = (t & 3) * 16;
            const short* sh = WfhT_hi + (size_t)(d0 + r) * HH + h0 + hb;
            *(short8*)&Bhi[r][hb]     = *(const short8*)sh;
            *(short8*)&Bhi[r][hb + 8] = *(const short8*)(sh + 8);
        }
        __syncthreads();
        #pragma unroll
        for (int kt = 0; kt < 2; ++kt) {
            const int kk = kt * 32 + lg * 8;
            short8 ahi = *(const short8*)&Ahi[wm * 16 + lr][kk];
            short8 alo = *(const short8*)&Alo[wm * 16 + lr][kk];
            #pragma unroll
            for (int nt = 0; nt < 4; ++nt) {
                short8 bhi = *(const short8*)&Bhi[wn * 64 + nt * 16 + lr][kk];
                acc[nt] = __builtin_amdgcn_mfma_f32_16x16x32_bf16(ahi, bhi, acc[nt], 0, 0, 0);
                acc[nt] = __builtin_amdgcn_mfma_f32_16x16x32_bf16(alo, bhi, acc[nt], 0, 0, 0);
            }
        }
    }

    // num/ns: reduce across the 8 threads sharing each row (same wave)
    #pragma unroll
    for (int off = 1; off < 8; off <<= 1) {
        pnum += __shfl_xor(pnum, off);
        pns  += __shfl_xor(pns, off);
    }
    if ((t & 7) == 0) { sred[ar][0] = pnum; sred[ar][1] = pns; }
    __syncthreads();
    if (t < 64) {
        float cosv = sred[t][0] / (fmaxf(sqrtf(sred[t][1]), 1e-8f) * sqrtf(2048.0f));
        strenL[t] = 1.0f / (1.0f + expf(-cosv));
    }
    __syncthreads();

    #pragma unroll
    for (int nt = 0; nt < 4; ++nt) {
        #pragma unroll
        for (int j = 0; j < 4; ++j) {
            int rloc = wm * 16 + lg * 4 + j;
            int col = d0 + wn * 64 + nt * 16 + lr;
            size_t gi = (size_t)(row0 + rloc) * DD + col;
            out[gi] = mixed[gi] + (acc[nt][j] + bfh[col]) * strenL[rloc];
        }
    }
}

extern "C" void kernel_launch(void* const* d_in, const int* in_sizes, int n_in,
                              void* d_out, int out_size, void* d_ws, size_t ws_size,
                              hipStream_t stream) {
    const float* states    = (const float*)d_in[0];
    const float* actions   = (const float*)d_in[1];
    const float* mem       = (const float*)d_in[2];
    const float* Wq        = (const float*)d_in[3];
    const float* bq        = (const float*)d_in[4];
    const float* Wk        = (const float*)d_in[5];
    const float* bk        = (const float*)d_in[6];
    const float* log_temp  = (const float*)d_in[7];
    const float* Wc        = (const float*)d_in[8];
    const float* bc        = (const float*)d_in[9];
    const float* temp_coal = (const float*)d_in[10];
    const float* W2h       = (const float*)d_in[11];
    const float* b2h       = (const float*)d_in[12];
    const float* Wfh       = (const float*)d_in[13];
    const float* bfh       = (const float*)d_in[14];
    const float* keys      = (const float*)d_in[15];
    const float* pos_codes = (const float*)d_in[16];
    const int*   step      = (const int*)d_in[17];
    float* out = (float*)d_out;

    float* ws = (float*)d_ws;
    float* mixed    = ws;                                    // 2,097,152 f32
    short* W2hT_hi  = (short*)(mixed + 2097152);             // 524288 shorts
    short* W2hT_lo  = W2hT_hi + 524288;
    short* WfhT_hi  = W2hT_lo + 524288;
    short* WfhT_lo  = WfhT_hi + 524288;
    unsigned short* qbits = (unsigned short*)(WfhT_lo + 524288);  // 1,048,576 u16
    float* Q        = (float*)(qbits + 1048576);             // 524288 f32
    float* K        = Q + 524288;
    float* incoming = K + 524288;                            // 2,097,152 f32
    short* pn_bf    = (short*)(incoming + 2097152);          // 524288 shorts
    float* selw     = (float*)(pn_bf + 524288);              // 131072 f32
    int*   seli     = (int*)(selw + 131072);                 // 131072 i32

    proj_kernel<<<BATCH * NN / 4, 64, 0, stream>>>(actions, Wq, bq, Wk, bk, Wc, bc, Q, K, pn_bf);
    prep_kernel<<<1024, 256, 0, stream>>>(W2h, Wfh, W2hT_hi, W2hT_lo, WfhT_hi, WfhT_lo);
    attn_score_kernel<<<BATCH * NN / 8, 512, 0, stream>>>(Q, K, log_temp, selw, seli);
    gather_kernel<<<BATCH * NN / 4, 256, 0, stream>>>(selw, seli, states, incoming);
    coal_kernel<<<BATCH * (NN / 32) * 2, 256, 0, stream>>>(pn_bf, incoming, temp_coal, mixed);
    hdcA_kernel<<<(BATCH * NN / 32) * 8, 256, 0, stream>>>(mixed, W2hT_hi, W2hT_lo, b2h, qbits);
    hdcB_kernel<<<(BATCH * NN / 64) * 2, 512, 0, stream>>>(mem, qbits, pos_codes, step,
                                                           WfhT_hi, bfh, keys, mixed, out);
}